// Round 4
// baseline (245.840 us; speedup 1.0000x reference)
//
#include <hip/hip_runtime.h>
#include <hip/hip_bf16.h>
#include <stdint.h>

// Problem constants (fixed by reference): N=8192 tokens, D=1024, U=512, E=8, B=8 bases.
#define NTOK 8192
#define DDIM 1024
#define UDIM 512
#define NEXP 8

typedef __attribute__((ext_vector_type(8))) short bf16x8;
typedef __attribute__((ext_vector_type(4))) float f32x4;

// ---- helpers ---------------------------------------------------------------

__device__ __forceinline__ unsigned short f2bf(float f) {
  unsigned int u = __float_as_uint(f);
  u += 0x7FFFu + ((u >> 16) & 1u);
  return (unsigned short)(u >> 16);
}

__device__ __forceinline__ void gload16(const void* g, void* lds) {
  // async global->LDS, 16B/lane; LDS dest = wave-uniform base + lane*16 (HW rule)
  __builtin_amdgcn_global_load_lds(
      (__attribute__((address_space(1))) void*)(uintptr_t)g,
      (__attribute__((address_space(3))) void*)(uint32_t)(uintptr_t)lds,
      16, 0, 0);
}

// ---- fused prep: x -> bf16 AND gating logits/argmax (reads x ONCE) ---------

__global__ void k_prep(const float* __restrict__ x, const float* __restrict__ Wg,
                       const float* __restrict__ bg, unsigned short* __restrict__ xbf,
                       int* __restrict__ eidx, int* __restrict__ counts) {
  const int lane = threadIdx.x & 63;
  const int n = (blockIdx.x << 2) + (threadIdx.x >> 6);  // 4 waves/block, 1 token/wave
  const float* xr = x + (size_t)n * DDIM;
  unsigned short* xo = xbf + (size_t)n * DDIM;
  float acc[8] = {0.f, 0.f, 0.f, 0.f, 0.f, 0.f, 0.f, 0.f};
#pragma unroll
  for (int c = 0; c < 4; ++c) {
    const int d = c * 256 + lane * 4;
    const float4 v = *(const float4*)(xr + d);
    ushort4 o;
    o.x = f2bf(v.x); o.y = f2bf(v.y); o.z = f2bf(v.z); o.w = f2bf(v.w);
    *(ushort4*)(xo + d) = o;
    const float vv[4] = {v.x, v.y, v.z, v.w};
#pragma unroll
    for (int q = 0; q < 4; ++q) {
      const float4 wa = *(const float4*)(Wg + (size_t)(d + q) * 8);
      const float4 wb = *(const float4*)(Wg + (size_t)(d + q) * 8 + 4);
      acc[0] = fmaf(vv[q], wa.x, acc[0]);
      acc[1] = fmaf(vv[q], wa.y, acc[1]);
      acc[2] = fmaf(vv[q], wa.z, acc[2]);
      acc[3] = fmaf(vv[q], wa.w, acc[3]);
      acc[4] = fmaf(vv[q], wb.x, acc[4]);
      acc[5] = fmaf(vv[q], wb.y, acc[5]);
      acc[6] = fmaf(vv[q], wb.z, acc[6]);
      acc[7] = fmaf(vv[q], wb.w, acc[7]);
    }
  }
#pragma unroll
  for (int e = 0; e < 8; ++e) {
#pragma unroll
    for (int o = 32; o > 0; o >>= 1) acc[e] += __shfl_xor(acc[e], o, 64);
  }
  if (lane == 0) {
    int best = 0;
    float bv = acc[0] + bg[0];
#pragma unroll
    for (int e2 = 1; e2 < 8; ++e2) {
      const float v = acc[e2] + bg[e2];
      if (v > bv) { bv = v; best = e2; }  // strict > = np.argmax first-index ties
    }
    eidx[n] = best;
    atomicAdd(counts + best, 1);
  }
}

// ---- prep: transpose [E][R][C] f32 -> [E][C][R] bf16 (128B store segments) --

__global__ void k_transpose(const float* __restrict__ src, unsigned short* __restrict__ dst,
                            int R, int C) {
  __shared__ float tile[64][33];
  const int e  = blockIdx.z;
  const int r0 = blockIdx.y << 6;
  const int c0 = blockIdx.x << 5;
  const float* s = src + (size_t)e * R * C;
  unsigned short* d = dst + (size_t)e * R * C;
  const int tc = threadIdx.x & 31, tr = threadIdx.x >> 5;  // tr 0..7
#pragma unroll
  for (int i = 0; i < 64; i += 8)
    tile[tr + i][tc] = s[(size_t)(r0 + tr + i) * C + c0 + tc];
  __syncthreads();
  const int rr = threadIdx.x & 63, cc = threadIdx.x >> 6;  // cc 0..3
#pragma unroll
  for (int i = 0; i < 32; i += 4)
    d[(size_t)(c0 + cc + i) * R + r0 + rr] = f2bf(tile[rr][cc + i]);
}

// ---- tiny scan + scatter ---------------------------------------------------

__global__ void k_scan(const int* __restrict__ counts, int* __restrict__ offsets,
                       int* __restrict__ cursors) {
  if (threadIdx.x == 0) {
    int run = 0;
    for (int e = 0; e < NEXP; ++e) { offsets[e] = run; cursors[e] = run; run += counts[e]; }
  }
}

__global__ void k_scatter(const int* __restrict__ eidx, int* __restrict__ cursors,
                          int* __restrict__ perm) {
  const int n = blockIdx.x * blockDim.x + threadIdx.x;
  const int e = eidx[n];
  const int pos = atomicAdd(cursors + e, 1);
  perm[pos] = n;  // order within expert nondeterministic; per-token output unaffected
}

// ---- fused expert kernel ---------------------------------------------------
// Block: 512 threads = 8 waves; tile = 64 tokens (one expert) x full U=512.
// Double-buffered A/B staging, m97-style schedule: stage(k+1) -> compute(k) -> sync.
// LDS: union{A 8KB + B 64KB | ctrl 16KB} + H 64KB + misc 4.3KB = 140.3KB (1 block/CU).

struct __align__(16) ExpSmem {
  union {
    struct {
      short Ab[2][64 * 32];    // A k-slice  [row][4 slots x 8 bf16], XOR-swizzled slots
      short Bb[2][512 * 32];   // B k-slice  [col][4 slots x 8 bf16], XOR-swizzled slots
    } g;
    float ctrl_s[8 * 512];     // epilogue-2 only, after all A/B staging done
  } u;
  short Hs[64 * 512];          // swish output bf16, byte ^= ((row&7)<<4) swizzle
  float b1_s[512];
  float scal_s[512];
  int rows_s[64];
};

__global__ __launch_bounds__(512) void k_expert(
    const unsigned short* __restrict__ xbf,   // [N][D] bf16
    const unsigned short* __restrict__ W1t,   // [E][U][D] bf16
    const unsigned short* __restrict__ projT, // [E][V][U] bf16
    const float* __restrict__ b1,             // [E][U]
    const float* __restrict__ ctrl,           // [E][8][U]
    const float* __restrict__ scaling,        // [E][U]
    const int* __restrict__ perm,
    const int* __restrict__ counts,
    const int* __restrict__ offsets,
    float* __restrict__ out)                  // [N][U] f32
{
  __shared__ ExpSmem sm;

  const int e    = blockIdx.x & 7;    // expert -> XCD (id%8): weight stream L2-local
  const int tile = blockIdx.x >> 3;
  const int cnt  = counts[e];
  if (tile * 64 >= cnt) return;
  const int off = offsets[e];
  const int m   = min(64, cnt - tile * 64);

  const int t    = threadIdx.x;
  const int w    = t >> 6;
  const int lane = t & 63;
  const int ln15 = lane & 15;
  const int g    = lane >> 4;                // k-group of this lane's fragment
  const int slot2 = g ^ ((ln15 >> 1) & 3);   // physical slot; (row>>1)&3 swizzle -> 2-way max

  // ---- per-expert params + row ids ----
  sm.b1_s[t]   = b1[e * UDIM + t];
  sm.scal_s[t] = scaling[e * UDIM + t];
  if (t < 64) {
    const int idx = tile * 64 + t;
    sm.rows_s[t] = perm[off + (idx < cnt ? idx : 0)];  // pad with a valid token
  }
  __syncthreads();

  const unsigned short* W1e = W1t + ((size_t)e << 19);    // e*512*1024
  const unsigned short* pje = projT + ((size_t)e << 18);  // e*512*512

  // staging: source k-chunk pre-swizzled so LDS stays linear (both-sides rule, G21)
  auto stageA = [&](int k0, int buf) {
    if (t < 256) {  // 64 rows x 32 k (4KB)
      const int row = t >> 2, h = t & 3;
      gload16(xbf + (size_t)sm.rows_s[row] * DDIM + (k0 + ((h ^ ((row >> 1) & 3)) << 3)),
              (char*)sm.u.g.Ab[buf] + (t & ~63) * 16);
    }
  };
  auto stageB = [&](const unsigned short* base, int ldk, int k0, int buf) {
#pragma unroll
    for (int j = 0; j < 4; ++j) {  // 512 cols x 32 k (32KB)
      const int c = t + j * 512;
      const int u2 = c >> 2, h = c & 3;
      gload16(base + (size_t)u2 * ldk + (k0 + ((h ^ ((u2 >> 1) & 3)) << 3)),
              (char*)sm.u.g.Bb[buf] + (c & ~63) * 16);
    }
  };

  const f32x4 zero4 = {0.f, 0.f, 0.f, 0.f};

  // ======== GEMM1: H = swish(X @ W1[e] + b1[e]), K = 1024 ========
  f32x4 acc[4][4];
#pragma unroll
  for (int a = 0; a < 4; ++a)
#pragma unroll
    for (int b = 0; b < 4; ++b) acc[a][b] = zero4;

  stageA(0, 0); stageB(W1e, DDIM, 0, 0);
  __syncthreads();
  int cur = 0;
  for (int k0 = 0; k0 < DDIM; k0 += 32) {
    if (k0 + 32 < DDIM) { stageA(k0 + 32, cur ^ 1); stageB(W1e, DDIM, k0 + 32, cur ^ 1); }
    bf16x8 af[4], bfr[4];
#pragma unroll
    for (int mt = 0; mt < 4; ++mt)
      af[mt] = *(const bf16x8*)((const char*)sm.u.g.Ab[cur] + (mt * 16 + ln15) * 64 + slot2 * 16);
#pragma unroll
    for (int nt = 0; nt < 4; ++nt)
      bfr[nt] = *(const bf16x8*)((const char*)sm.u.g.Bb[cur] + (w * 64 + nt * 16 + ln15) * 64 + slot2 * 16);
#pragma unroll
    for (int mt = 0; mt < 4; ++mt)
#pragma unroll
      for (int nt = 0; nt < 4; ++nt)
        acc[mt][nt] = __builtin_amdgcn_mfma_f32_16x16x32_bf16(af[mt], bfr[nt], acc[mt][nt], 0, 0, 0);
    __syncthreads();  // drains prefetch vmcnt + guards buffer swap
    cur ^= 1;
  }

  // issue GEMM2's first B tile NOW so its latency hides under epilogue-1 VALU
  stageB(pje, UDIM, 0, 0);

  // ---- epilogue1: +b1, swish -> Hs (bf16, XOR-swizzled) ----
#pragma unroll
  for (int mt = 0; mt < 4; ++mt) {
#pragma unroll
    for (int nt = 0; nt < 4; ++nt) {
#pragma unroll
      for (int r = 0; r < 4; ++r) {
        const int row = mt * 16 + g * 4 + r;      // C layout: row=(lane>>4)*4+reg
        const int col = w * 64 + nt * 16 + ln15;  //           col=lane&15
        const float a  = acc[mt][nt][r] + sm.b1_s[col];
        const float hv = a / (1.f + __expf(-a));
        *(unsigned short*)((char*)sm.Hs + row * 1024 + ((col * 2) ^ ((row & 7) << 4))) = f2bf(hv);
      }
    }
  }
  __syncthreads();

  // ======== GEMM2: Z = H @ proj[e], K = 512 ========
  f32x4 acc2[4][4];
#pragma unroll
  for (int a = 0; a < 4; ++a)
#pragma unroll
    for (int b = 0; b < 4; ++b) acc2[a][b] = zero4;

  cur = 0;
  for (int ks = 0; ks < UDIM; ks += 32) {
    if (ks + 32 < UDIM) stageB(pje, UDIM, ks + 32, cur ^ 1);
    bf16x8 af2[4], bfr2[4];
#pragma unroll
    for (int mt = 0; mt < 4; ++mt)
      af2[mt] = *(const bf16x8*)((const char*)sm.Hs + (mt * 16 + ln15) * 1024 +
                                 ((ks * 2 + g * 16) ^ ((ln15 & 7) << 4)));
#pragma unroll
    for (int nt = 0; nt < 4; ++nt)
      bfr2[nt] = *(const bf16x8*)((const char*)sm.u.g.Bb[cur] + (w * 64 + nt * 16 + ln15) * 64 + slot2 * 16);
#pragma unroll
    for (int mt = 0; mt < 4; ++mt)
#pragma unroll
      for (int nt = 0; nt < 4; ++nt)
        acc2[mt][nt] = __builtin_amdgcn_mfma_f32_16x16x32_bf16(af2[mt], bfr2[nt], acc2[mt][nt], 0, 0, 0);
    __syncthreads();
    cur ^= 1;
  }

  // ---- epilogue2: stage ctrl into (now free) union region, then RBF + store ----
#pragma unroll
  for (int j = 0; j < 8; ++j)
    sm.u.ctrl_s[t + j * 512] = ctrl[e * 8 * UDIM + t + j * 512];
  __syncthreads();

  const float kInv7 = 0.14285714285714285f;  // knots = b/7
#pragma unroll
  for (int mt = 0; mt < 4; ++mt) {
#pragma unroll
    for (int nt = 0; nt < 4; ++nt) {
#pragma unroll
      for (int r = 0; r < 4; ++r) {
        const int row = mt * 16 + g * 4 + r;
        if (row < m) {
          const int col = w * 64 + nt * 16 + ln15;
          const float z  = acc2[mt][nt][r];
          const float xn = 1.f / (1.f + __expf(-z));
          float s = 0.f, dc = 0.f;
#pragma unroll
          for (int b = 0; b < 8; ++b) {
            const float d   = xn - (float)b * kInv7;
            const float bas = __expf(-32.f * d * d);   // exp(-dist/(2*(1/8)^2))
            s += bas;
            dc = fmaf(bas, sm.u.ctrl_s[b * 512 + col], dc);
          }
          out[(size_t)sm.rows_s[row] * UDIM + col] = dc / (s + 1e-6f) * sm.scal_s[col];
        }
      }
    }
  }
}

// ---- host launch -----------------------------------------------------------

extern "C" void kernel_launch(void* const* d_in, const int* in_sizes, int n_in,
                              void* d_out, int out_size, void* d_ws, size_t ws_size,
                              hipStream_t stream) {
  const float* x       = (const float*)d_in[0];
  const float* W1      = (const float*)d_in[1];
  const float* b1      = (const float*)d_in[2];
  const float* proj    = (const float*)d_in[3];
  const float* ctrl    = (const float*)d_in[4];
  const float* scaling = (const float*)d_in[5];
  const float* Wg      = (const float*)d_in[6];
  const float* bg      = (const float*)d_in[7];
  float* out = (float*)d_out;
  char* ws = (char*)d_ws;

  // workspace layout (~28.2 MB total)
  int* eidx    = (int*)(ws + 0);            // 32KB
  int* perm    = (int*)(ws + 32768);        // 32KB
  int* counts  = (int*)(ws + 65536);        // 32B
  int* offsets = (int*)(ws + 65536 + 32);   // 32B
  int* cursors = (int*)(ws + 65536 + 64);   // 32B
  unsigned short* xbf   = (unsigned short*)(ws + 131072);                        // 16MB
  unsigned short* W1t   = (unsigned short*)(ws + 131072 + 16777216);             // 8MB
  unsigned short* projT = (unsigned short*)(ws + 131072 + 16777216 + 8388608);   // 4MB

  hipMemsetAsync(ws + 65536, 0, 128, stream);

  k_prep<<<NTOK / 4, 256, 0, stream>>>(x, Wg, bg, xbf, eidx, counts);
  k_transpose<<<dim3(UDIM / 32, DDIM / 64, NEXP), 256, 0, stream>>>(W1, W1t, DDIM, UDIM);
  k_transpose<<<dim3(UDIM / 32, UDIM / 64, NEXP), 256, 0, stream>>>(proj, projT, UDIM, UDIM);
  k_scan<<<1, 64, 0, stream>>>(counts, offsets, cursors);
  k_scatter<<<NTOK / 256, 256, 0, stream>>>(eidx, cursors, perm);
  k_expert<<<NEXP * (NTOK / 64), 512, 0, stream>>>(xbf, W1t, projT, b1, ctrl, scaling,
                                                   perm, counts, offsets, out);
}

// Round 5
// 202.982 us; speedup vs baseline: 1.2111x; 1.2111x over previous
//
#include <hip/hip_runtime.h>
#include <hip/hip_bf16.h>
#include <stdint.h>

// Problem constants: N=8192 tokens, D=1024, U=512, E=8, B=8 bases.
#define NTOK 8192
#define DDIM 1024
#define UDIM 512
#define NEXP 8
#define MT_MAX 136   // max padded 64-row M-tiles: floor(8192/64) + 7 experts' partials + slack

typedef __attribute__((ext_vector_type(8))) short bf16x8;
typedef __attribute__((ext_vector_type(4))) float f32x4;

// ---- helpers ---------------------------------------------------------------

__device__ __forceinline__ unsigned short f2bf(float f) {
  unsigned int u = __float_as_uint(f);
  u += 0x7FFFu + ((u >> 16) & 1u);
  return (unsigned short)(u >> 16);
}

__device__ __forceinline__ void gload16(const void* g, void* lds) {
  // async global->LDS, 16B/lane; LDS dest = wave-uniform base + lane*16 (HW rule)
  __builtin_amdgcn_global_load_lds(
      (__attribute__((address_space(1))) void*)(uintptr_t)g,
      (__attribute__((address_space(3))) void*)(uint32_t)(uintptr_t)lds,
      16, 0, 0);
}

// ---- gating: f32 logits + first-index argmax (1 wave / token) --------------

__global__ void k_prep(const float* __restrict__ x, const float* __restrict__ Wg,
                       const float* __restrict__ bg, int* __restrict__ eidx,
                       int* __restrict__ counts) {
  const int lane = threadIdx.x & 63;
  const int n = (blockIdx.x << 2) + (threadIdx.x >> 6);
  const float* xr = x + (size_t)n * DDIM;
  float acc[8] = {0.f, 0.f, 0.f, 0.f, 0.f, 0.f, 0.f, 0.f};
#pragma unroll
  for (int c = 0; c < 16; ++c) {
    const int d = c * 64 + lane;
    const float xv = xr[d];
    const float4 wa = *(const float4*)(Wg + (size_t)d * 8);
    const float4 wb = *(const float4*)(Wg + (size_t)d * 8 + 4);
    acc[0] = fmaf(xv, wa.x, acc[0]); acc[1] = fmaf(xv, wa.y, acc[1]);
    acc[2] = fmaf(xv, wa.z, acc[2]); acc[3] = fmaf(xv, wa.w, acc[3]);
    acc[4] = fmaf(xv, wb.x, acc[4]); acc[5] = fmaf(xv, wb.y, acc[5]);
    acc[6] = fmaf(xv, wb.z, acc[6]); acc[7] = fmaf(xv, wb.w, acc[7]);
  }
#pragma unroll
  for (int e = 0; e < 8; ++e) {
#pragma unroll
    for (int o = 32; o > 0; o >>= 1) acc[e] += __shfl_xor(acc[e], o, 64);
  }
  if (lane == 0) {
    int best = 0;
    float bv = acc[0] + bg[0];
#pragma unroll
    for (int e2 = 1; e2 < 8; ++e2) {
      const float v = acc[e2] + bg[e2];
      if (v > bv) { bv = v; best = e2; }  // strict > = np.argmax first-index ties
    }
    eidx[n] = best;
    atomicAdd(counts + best, 1);
  }
}

// ---- pack weights: src[R][C] f32 -> panels [R/32 kt][C][32] bf16 (linear) ---
// z<8: W1 expert z (R=1024); z>=8: proj expert z-8 (R=512). C=512 for both.

__global__ void k_pack(const float* __restrict__ W1, const float* __restrict__ proj,
                       unsigned short* __restrict__ W1p, unsigned short* __restrict__ projp) {
  __shared__ float tile[64][65];
  const int z = blockIdx.z;
  const int R = (z < 8) ? DDIM : UDIM;
  const int r0 = blockIdx.y << 6;
  if (r0 >= R) return;
  const int c0 = blockIdx.x << 6;
  const float* src = (z < 8) ? (W1 + (size_t)z * DDIM * UDIM)
                             : (proj + (size_t)(z - 8) * UDIM * UDIM);
  unsigned short* dst = (z < 8) ? (W1p + (size_t)z * DDIM * UDIM)
                                : (projp + (size_t)(z - 8) * UDIM * UDIM);
  const int t = threadIdx.x;
#pragma unroll
  for (int i = 0; i < 4; ++i) {
    const int ri = (t >> 4) + i * 16;
    const int ci = (t & 15) * 4;
    const float4 v = *(const float4*)(src + (size_t)(r0 + ri) * UDIM + c0 + ci);
    tile[ri][ci] = v.x; tile[ri][ci + 1] = v.y; tile[ri][ci + 2] = v.z; tile[ri][ci + 3] = v.w;
  }
  __syncthreads();
  const int cc = t >> 2, ch = t & 3;
#pragma unroll
  for (int j = 0; j < 2; ++j) {
    const int kt = (r0 >> 5) + j;
    union { bf16x8 v; unsigned short u[8]; } pk;
#pragma unroll
    for (int q = 0; q < 8; ++q) pk.u[q] = f2bf(tile[j * 32 + ch * 8 + q][cc]);
    *(bf16x8*)(dst + ((size_t)kt * UDIM + c0 + cc) * 32 + ch * 8) = pk.v;
  }
}

// ---- scan: padded segment offsets + tile maps (single thread, trivial) -----

__global__ void k_scan(const int* __restrict__ counts, int* __restrict__ cursors,
                       int* __restrict__ tile_expert, int* __restrict__ tile_rowlim) {
  if (threadIdx.x == 0) {
    int run = 0;  // in tokens, 64-aligned
    for (int e = 0; e < NEXP; ++e) {
      cursors[e] = run;
      const int cnt = counts[e];
      const int tiles = (cnt + 63) >> 6;
      for (int tI = 0; tI < tiles; ++tI) {
        tile_expert[(run >> 6) + tI] = e;
        const int rl = cnt - tI * 64;
        tile_rowlim[(run >> 6) + tI] = rl < 64 ? rl : 64;
      }
      run += tiles << 6;
    }
    for (int tI = run >> 6; tI < MT_MAX; ++tI) { tile_expert[tI] = -1; tile_rowlim[tI] = 0; }
  }
}

__global__ void k_scatter(const int* __restrict__ eidx, int* __restrict__ cursors,
                          int* __restrict__ perm_p) {
  const int n = blockIdx.x * blockDim.x + threadIdx.x;
  const int e = eidx[n];
  const int pos = atomicAdd(cursors + e, 1);
  perm_p[pos] = n;  // within-expert order nondeterministic; per-token output unaffected
}

// ---- GEMM1: H[pos][u] = swish(x[tok] @ W1[e] + b1[e]) -> Hp panels bf16 ----
// 64x64 tile, BK=32, 4 waves (2x2), 16KB LDS dbuf -> high occupancy (TLP).

__global__ __launch_bounds__(256) void k_gemm1(
    const float* __restrict__ x, const unsigned short* __restrict__ W1p,
    const float* __restrict__ b1, const int* __restrict__ perm_p,
    const int* __restrict__ tile_expert, const int* __restrict__ tile_rowlim,
    unsigned short* __restrict__ Hp) {
  __shared__ short Ab[2][64 * 32];
  __shared__ short Bb[2][64 * 32];
  __shared__ int rows_s[64];

  const int Mt = blockIdx.x;
  const int e = tile_expert[Mt];
  if (e < 0) return;
  const int Nt = blockIdx.y;
  const int rowlim = tile_rowlim[Mt];

  const int t = threadIdx.x;
  const int w = t >> 6, wr = w >> 1, wc = w & 1;
  const int lane = t & 63, ln15 = lane & 15, g = lane >> 4;

  if (t < 64) {
    const int src = Mt * 64 + (t < rowlim ? t : 0);
    rows_s[t] = perm_p[src];
  }
  __syncthreads();

  const int srow = t >> 2;                    // staging row/col (0..63)
  const int sh = (t & 3) ^ ((srow >> 1) & 3); // source chunk for this LDS slot
  const unsigned short* Bpan0 = W1p + ((size_t)e * 32 * UDIM + Nt * 64) * 32;
  const float* xrow = x + (size_t)rows_s[srow] * DDIM + sh * 8;

  float4 av0, av1;
  auto issueA = [&](int kt) {
    const float* s = xrow + kt * 32;
    av0 = *(const float4*)s; av1 = *(const float4*)(s + 4);
  };
  auto writeA = [&](int buf) {
    union { bf16x8 v; unsigned short u[8]; } pk;
    pk.u[0] = f2bf(av0.x); pk.u[1] = f2bf(av0.y); pk.u[2] = f2bf(av0.z); pk.u[3] = f2bf(av0.w);
    pk.u[4] = f2bf(av1.x); pk.u[5] = f2bf(av1.y); pk.u[6] = f2bf(av1.z); pk.u[7] = f2bf(av1.w);
    *(bf16x8*)((char*)Ab[buf] + t * 16) = pk.v;
  };
  auto issueB = [&](int kt, int buf) {
    gload16(Bpan0 + (size_t)kt * UDIM * 32 + srow * 32 + sh * 8,
            (char*)Bb[buf] + (t & ~63) * 16);
  };

  f32x4 acc[2][2];
  const f32x4 z4 = {0.f, 0.f, 0.f, 0.f};
  acc[0][0] = z4; acc[0][1] = z4; acc[1][0] = z4; acc[1][1] = z4;

  issueA(0); issueB(0, 0); writeA(0);
  __syncthreads();
  int cur = 0;
  for (int kt = 0; kt < 32; ++kt) {
    const int nb = cur ^ 1;
    if (kt < 31) { issueA(kt + 1); issueB(kt + 1, nb); }
    bf16x8 af[2], bf_[2];
#pragma unroll
    for (int mt = 0; mt < 2; ++mt) {
      const int r = wr * 32 + mt * 16 + ln15;
      af[mt] = *(const bf16x8*)((const char*)Ab[cur] + r * 64 + (g ^ ((r >> 1) & 3)) * 16);
    }
#pragma unroll
    for (int nt = 0; nt < 2; ++nt) {
      const int c = wc * 32 + nt * 16 + ln15;
      bf_[nt] = *(const bf16x8*)((const char*)Bb[cur] + c * 64 + (g ^ ((c >> 1) & 3)) * 16);
    }
#pragma unroll
    for (int mt = 0; mt < 2; ++mt)
#pragma unroll
      for (int nt = 0; nt < 2; ++nt)
        acc[mt][nt] = __builtin_amdgcn_mfma_f32_16x16x32_bf16(af[mt], bf_[nt], acc[mt][nt], 0, 0, 0);
    if (kt < 31) writeA(nb);  // vmcnt-waited cvt+ds_write overlaps next B gload
    __syncthreads();
    cur = nb;
  }

  // epilogue: +b1, swish, store bf16 into Hp panel-major (linear chunks)
  float bv[2];
#pragma unroll
  for (int nt = 0; nt < 2; ++nt)
    bv[nt] = b1[e * UDIM + Nt * 64 + wc * 32 + nt * 16 + ln15];
#pragma unroll
  for (int mt = 0; mt < 2; ++mt) {
#pragma unroll
    for (int nt = 0; nt < 2; ++nt) {
      const int colin = wc * 32 + nt * 16 + ln15;
      unsigned short* hp = Hp + (((size_t)Mt * 16 + Nt * 2 + (colin >> 5)) * 64) * 32 + (colin & 31);
#pragma unroll
      for (int r = 0; r < 4; ++r) {
        const int row = wr * 32 + mt * 16 + g * 4 + r;
        const float a = acc[mt][nt][r] + bv[nt];
        hp[(size_t)row * 32] = f2bf(a / (1.f + __expf(-a)));
      }
    }
  }
}

// ---- GEMM2: Z = H @ proj[e]; epilogue sigmoid->RBF->ctrl->scale->scatter ---

__global__ __launch_bounds__(256) void k_gemm2(
    const unsigned short* __restrict__ Hp, const unsigned short* __restrict__ projp,
    const float* __restrict__ ctrl, const float* __restrict__ scaling,
    const int* __restrict__ perm_p, const int* __restrict__ tile_expert,
    const int* __restrict__ tile_rowlim, float* __restrict__ out) {
  __shared__ short Ab[2][64 * 32];
  __shared__ short Bb[2][64 * 32];
  __shared__ int tok_s[64];

  const int Mt = blockIdx.x;
  const int e = tile_expert[Mt];
  if (e < 0) return;
  const int Nt = blockIdx.y;
  const int rowlim = tile_rowlim[Mt];

  const int t = threadIdx.x;
  const int w = t >> 6, wr = w >> 1, wc = w & 1;
  const int lane = t & 63, ln15 = lane & 15, g = lane >> 4;

  if (t < 64) tok_s[t] = perm_p[Mt * 64 + (t < rowlim ? t : 0)];
  __syncthreads();

  const int srow = t >> 2;
  const int sh = (t & 3) ^ ((srow >> 1) & 3);
  const unsigned short* Apan0 = Hp + ((size_t)Mt * 16 * 64) * 32;
  const unsigned short* Bpan0 = projp + ((size_t)e * 16 * UDIM + Nt * 64) * 32;

  auto stage = [&](int kt, int buf) {
    gload16(Apan0 + (size_t)kt * 64 * 32 + srow * 32 + sh * 8,
            (char*)Ab[buf] + (t & ~63) * 16);
    gload16(Bpan0 + (size_t)kt * UDIM * 32 + srow * 32 + sh * 8,
            (char*)Bb[buf] + (t & ~63) * 16);
  };

  f32x4 acc[2][2];
  const f32x4 z4 = {0.f, 0.f, 0.f, 0.f};
  acc[0][0] = z4; acc[0][1] = z4; acc[1][0] = z4; acc[1][1] = z4;

  stage(0, 0);
  __syncthreads();
  int cur = 0;
  for (int kt = 0; kt < 16; ++kt) {
    const int nb = cur ^ 1;
    if (kt < 15) stage(kt + 1, nb);
    bf16x8 af[2], bf_[2];
#pragma unroll
    for (int mt = 0; mt < 2; ++mt) {
      const int r = wr * 32 + mt * 16 + ln15;
      af[mt] = *(const bf16x8*)((const char*)Ab[cur] + r * 64 + (g ^ ((r >> 1) & 3)) * 16);
    }
#pragma unroll
    for (int nt = 0; nt < 2; ++nt) {
      const int c = wc * 32 + nt * 16 + ln15;
      bf_[nt] = *(const bf16x8*)((const char*)Bb[cur] + c * 64 + (g ^ ((c >> 1) & 3)) * 16);
    }
#pragma unroll
    for (int mt = 0; mt < 2; ++mt)
#pragma unroll
      for (int nt = 0; nt < 2; ++nt)
        acc[mt][nt] = __builtin_amdgcn_mfma_f32_16x16x32_bf16(af[mt], bf_[nt], acc[mt][nt], 0, 0, 0);
    __syncthreads();
    cur = nb;
  }

  // epilogue: sigmoid -> gaussian RBF basis -> ctrl dot -> scale -> scatter
  const float kInv7 = 0.14285714285714285f;  // knots = b/7
  float cv[2][8], sc[2];
#pragma unroll
  for (int nt = 0; nt < 2; ++nt) {
    const int colg = Nt * 64 + wc * 32 + nt * 16 + ln15;
    sc[nt] = scaling[e * UDIM + colg];
#pragma unroll
    for (int b = 0; b < 8; ++b) cv[nt][b] = ctrl[((size_t)e * 8 + b) * UDIM + colg];
  }
#pragma unroll
  for (int mt = 0; mt < 2; ++mt) {
#pragma unroll
    for (int r = 0; r < 4; ++r) {
      const int row = wr * 32 + mt * 16 + g * 4 + r;
      if (row < rowlim) {
        const int tok = tok_s[row];
#pragma unroll
        for (int nt = 0; nt < 2; ++nt) {
          const int colg = Nt * 64 + wc * 32 + nt * 16 + ln15;
          const float z = acc[mt][nt][r];
          const float xn = 1.f / (1.f + __expf(-z));
          float s = 0.f, dc = 0.f;
#pragma unroll
          for (int b = 0; b < 8; ++b) {
            const float d = xn - (float)b * kInv7;
            const float bas = __expf(-32.f * d * d);  // exp(-d^2/(2*(1/8)^2))
            s += bas;
            dc = fmaf(bas, cv[nt][b], dc);
          }
          out[(size_t)tok * UDIM + colg] = dc / (s + 1e-6f) * sc[nt];
        }
      }
    }
  }
}

// ---- host launch -----------------------------------------------------------

extern "C" void kernel_launch(void* const* d_in, const int* in_sizes, int n_in,
                              void* d_out, int out_size, void* d_ws, size_t ws_size,
                              hipStream_t stream) {
  const float* x       = (const float*)d_in[0];
  const float* W1      = (const float*)d_in[1];
  const float* b1      = (const float*)d_in[2];
  const float* proj    = (const float*)d_in[3];
  const float* ctrl    = (const float*)d_in[4];
  const float* scaling = (const float*)d_in[5];
  const float* Wg      = (const float*)d_in[6];
  const float* bg      = (const float*)d_in[7];
  float* out = (float*)d_out;
  char* ws = (char*)d_ws;

  // workspace layout (~20.7 MB)
  int* eidx        = (int*)(ws + 0);                 // 32KB
  int* perm_p      = (int*)(ws + 32768);             // 8704*4 = 34816B
  int* counts      = (int*)(ws + 69632);             // 32B
  int* cursors     = (int*)(ws + 69632 + 32);        // 32B
  int* tile_expert = (int*)(ws + 69632 + 64);        // 544B
  int* tile_rowlim = (int*)(ws + 69632 + 640);       // 544B
  unsigned short* W1p   = (unsigned short*)(ws + 131072);                       // 8MB
  unsigned short* projp = (unsigned short*)(ws + 131072 + 8388608);             // 4MB
  unsigned short* Hp    = (unsigned short*)(ws + 131072 + 8388608 + 4194304);   // 8.9MB

  hipMemsetAsync(counts, 0, 32, stream);

  k_prep<<<NTOK / 4, 256, 0, stream>>>(x, Wg, bg, eidx, counts);
  k_pack<<<dim3(UDIM / 64, DDIM / 64, 16), 256, 0, stream>>>(W1, proj, W1p, projp);
  k_scan<<<1, 64, 0, stream>>>(counts, cursors, tile_expert, tile_rowlim);
  k_scatter<<<NTOK / 256, 256, 0, stream>>>(eidx, cursors, perm_p);
  k_gemm1<<<dim3(MT_MAX, UDIM / 64), 256, 0, stream>>>(x, W1p, b1, perm_p,
                                                       tile_expert, tile_rowlim, Hp);
  k_gemm2<<<dim3(MT_MAX, UDIM / 64), 256, 0, stream>>>(Hp, projp, ctrl, scaling, perm_p,
                                                       tile_expert, tile_rowlim, out);
}

// Round 6
// 201.743 us; speedup vs baseline: 1.2186x; 1.0061x over previous
//
#include <hip/hip_runtime.h>
#include <hip/hip_bf16.h>
#include <stdint.h>

// Problem constants: N=8192 tokens, D=1024, U=512, E=8, B=8 bases.
#define NTOK 8192
#define DDIM 1024
#define UDIM 512
#define NEXP 8
#define MT_MAX 136   // max padded 64-row M-tiles: 8192/64 + 7 partials + slack

typedef __attribute__((ext_vector_type(8))) short bf16x8;
typedef __attribute__((ext_vector_type(4))) float f32x4;

// ---- helpers ---------------------------------------------------------------

__device__ __forceinline__ unsigned short f2bf(float f) {
  unsigned int u = __float_as_uint(f);
  u += 0x7FFFu + ((u >> 16) & 1u);
  return (unsigned short)(u >> 16);
}

__device__ __forceinline__ void gload16(const void* g, void* lds) {
  // async global->LDS, 16B/lane; LDS dest = wave-uniform base + lane*16 (HW rule)
  __builtin_amdgcn_global_load_lds(
      (__attribute__((address_space(1))) void*)(uintptr_t)g,
      (__attribute__((address_space(3))) void*)(uint32_t)(uintptr_t)lds,
      16, 0, 0);
}

// ---- gating v2: WgT in LDS (broadcast-friendly), coalesced x, f32 argmax ----
// Block = 256 thr = 4 token-waves. Lane l covers d in {c*256 + l*4 .. +3}.

__global__ __launch_bounds__(256) void k_prep(const float* __restrict__ x,
                                              const float* __restrict__ Wg,
                                              const float* __restrict__ bg,
                                              int* __restrict__ eidx,
                                              int* __restrict__ counts) {
  __shared__ float WgT[8][1040];  // transposed gate weights, padded row (33.3KB)
  const int t = threadIdx.x;
  // stage: Wg[1024][8] -> WgT[e][d]; global reads perfectly coalesced
#pragma unroll
  for (int r = 0; r < 32; ++r)
    WgT[t & 7][r * 32 + (t >> 3)] = Wg[r * 256 + t];
  __syncthreads();

  const int lane = t & 63;
  const int n = (blockIdx.x << 2) + (t >> 6);
  const float* xr = x + (size_t)n * DDIM;
  float acc[8] = {0.f, 0.f, 0.f, 0.f, 0.f, 0.f, 0.f, 0.f};
#pragma unroll
  for (int c = 0; c < 4; ++c) {
    const float4 xv = *(const float4*)(xr + c * 256 + lane * 4);
#pragma unroll
    for (int e = 0; e < 8; ++e) {
      const float4 wv = *(const float4*)(&WgT[e][c * 256 + lane * 4]);
      acc[e] = fmaf(xv.x, wv.x, acc[e]);
      acc[e] = fmaf(xv.y, wv.y, acc[e]);
      acc[e] = fmaf(xv.z, wv.z, acc[e]);
      acc[e] = fmaf(xv.w, wv.w, acc[e]);
    }
  }
#pragma unroll
  for (int e = 0; e < 8; ++e) {
#pragma unroll
    for (int o = 32; o > 0; o >>= 1) acc[e] += __shfl_xor(acc[e], o, 64);
  }
  if (lane == 0) {
    int best = 0;
    float bv = acc[0] + bg[0];
#pragma unroll
    for (int e2 = 1; e2 < 8; ++e2) {
      const float v = acc[e2] + bg[e2];
      if (v > bv) { bv = v; best = e2; }  // strict > = np.argmax first-index ties
    }
    eidx[n] = best;
    atomicAdd(counts + best, 1);
  }
}

// ---- pack weights: src[R][C] f32 -> panels [R/32 kt][C][32] bf16 (linear) ---
// z<8: W1 expert z (R=1024); z>=8: proj expert z-8 (R=512). C=512 for both.

__global__ void k_pack(const float* __restrict__ W1, const float* __restrict__ proj,
                       unsigned short* __restrict__ W1p, unsigned short* __restrict__ projp) {
  __shared__ float tile[64][65];
  const int z = blockIdx.z;
  const int R = (z < 8) ? DDIM : UDIM;
  const int r0 = blockIdx.y << 6;
  if (r0 >= R) return;
  const int c0 = blockIdx.x << 6;
  const float* src = (z < 8) ? (W1 + (size_t)z * DDIM * UDIM)
                             : (proj + (size_t)(z - 8) * UDIM * UDIM);
  unsigned short* dst = (z < 8) ? (W1p + (size_t)z * DDIM * UDIM)
                                : (projp + (size_t)(z - 8) * UDIM * UDIM);
  const int t = threadIdx.x;
#pragma unroll
  for (int i = 0; i < 4; ++i) {
    const int ri = (t >> 4) + i * 16;
    const int ci = (t & 15) * 4;
    const float4 v = *(const float4*)(src + (size_t)(r0 + ri) * UDIM + c0 + ci);
    tile[ri][ci] = v.x; tile[ri][ci + 1] = v.y; tile[ri][ci + 2] = v.z; tile[ri][ci + 3] = v.w;
  }
  __syncthreads();
  const int cc = t >> 2, ch = t & 3;
#pragma unroll
  for (int j = 0; j < 2; ++j) {
    const int kt = (r0 >> 5) + j;
    union { bf16x8 v; unsigned short u[8]; } pk;
#pragma unroll
    for (int q = 0; q < 8; ++q) pk.u[q] = f2bf(tile[j * 32 + ch * 8 + q][cc]);
    *(bf16x8*)(dst + ((size_t)kt * UDIM + c0 + cc) * 32 + ch * 8) = pk.v;
  }
}

// ---- scan (parallel): padded segment offsets + tile maps -------------------

__global__ void k_scan(const int* __restrict__ counts, int* __restrict__ cursors,
                       int* __restrict__ tile_expert, int* __restrict__ tile_rowlim) {
  __shared__ int cnt_s[8], tbase_s[9];
  const int t = threadIdx.x;
  if (t < 8) cnt_s[t] = counts[t];
  __syncthreads();
  if (t == 0) {
    int run = 0;
    for (int e = 0; e < 8; ++e) { tbase_s[e] = run; run += (cnt_s[e] + 63) >> 6; }
    tbase_s[8] = run;
  }
  __syncthreads();
  if (t < 8) cursors[t] = tbase_s[t] << 6;  // token base of padded segment
  for (int tile = t; tile < MT_MAX; tile += blockDim.x) {
    int e = -1, rl = 0;
#pragma unroll
    for (int q = 0; q < 8; ++q) {
      if (tile >= tbase_s[q] && tile < tbase_s[q + 1]) {
        e = q;
        const int r = cnt_s[q] - (tile - tbase_s[q]) * 64;
        rl = r < 64 ? r : 64;
      }
    }
    tile_expert[tile] = e;
    tile_rowlim[tile] = rl;
  }
}

__global__ void k_scatter(const int* __restrict__ eidx, int* __restrict__ cursors,
                          int* __restrict__ perm_p) {
  const int n = blockIdx.x * blockDim.x + threadIdx.x;
  const int e = eidx[n];
  const int pos = atomicAdd(cursors + e, 1);
  perm_p[pos] = n;  // within-expert order nondeterministic; per-token output unaffected
}

// ---- GEMM1: H = swish(x[tok] @ W1[e] + b1[e]) -> Hp panels bf16 ------------
// 64x128 tile, BK=32, 4 waves (2x2, each 32x64 out), 24KB LDS dbuf.

__global__ __launch_bounds__(256) void k_gemm1(
    const float* __restrict__ x, const unsigned short* __restrict__ W1p,
    const float* __restrict__ b1, const int* __restrict__ perm_p,
    const int* __restrict__ tile_expert, const int* __restrict__ tile_rowlim,
    unsigned short* __restrict__ Hp) {
  __shared__ __align__(16) short Ab[2][64 * 32];
  __shared__ __align__(16) short Bb[2][128 * 32];
  __shared__ int rows_s[64];

  const int Mt = blockIdx.x;
  const int e = tile_expert[Mt];
  if (e < 0) return;
  const int Nt = blockIdx.y;  // 0..3 (128-col slices)
  const int rowlim = tile_rowlim[Mt];

  const int t = threadIdx.x;
  const int w = t >> 6, wr = w >> 1, wc = w & 1;
  const int lane = t & 63, ln15 = lane & 15, g = lane >> 4;

  if (t < 64) rows_s[t] = perm_p[Mt * 64 + (t < rowlim ? t : 0)];
  __syncthreads();

  const int arow = t >> 2;
  const int ah = (t & 3) ^ ((arow >> 1) & 3);  // pre-swizzled source chunk (pairs read-side XOR)
  const float* xrow = x + (size_t)rows_s[arow] * DDIM + ah * 8;
  const unsigned short* Bpan = W1p + ((size_t)e * 32 * UDIM + Nt * 128) * 32;

  float4 av0, av1;
  auto issueA = [&](int kt) {
    const float* s = xrow + kt * 32;
    av0 = *(const float4*)s; av1 = *(const float4*)(s + 4);
  };
  auto writeA = [&](int buf) {
    union { bf16x8 v; unsigned short u[8]; } pk;
    pk.u[0] = f2bf(av0.x); pk.u[1] = f2bf(av0.y); pk.u[2] = f2bf(av0.z); pk.u[3] = f2bf(av0.w);
    pk.u[4] = f2bf(av1.x); pk.u[5] = f2bf(av1.y); pk.u[6] = f2bf(av1.z); pk.u[7] = f2bf(av1.w);
    *(bf16x8*)((char*)Ab[buf] + t * 16) = pk.v;
  };
  auto issueB = [&](int kt, int buf) {
#pragma unroll
    for (int j = 0; j < 2; ++j) {
      const int c = t + j * 256;
      const int u2 = c >> 2, h = (c & 3) ^ ((u2 >> 1) & 3);
      gload16(Bpan + (size_t)kt * UDIM * 32 + u2 * 32 + h * 8,
              (char*)Bb[buf] + (c & ~63) * 16);
    }
  };

  f32x4 acc[2][4];
  const f32x4 z4 = {0.f, 0.f, 0.f, 0.f};
#pragma unroll
  for (int a = 0; a < 2; ++a)
#pragma unroll
    for (int b = 0; b < 4; ++b) acc[a][b] = z4;

  issueA(0); issueB(0, 0); writeA(0);
  __syncthreads();
  int cur = 0;
  for (int kt = 0; kt < 32; ++kt) {
    const int nb = cur ^ 1;
    if (kt < 31) { issueA(kt + 1); issueB(kt + 1, nb); }
    bf16x8 af[2], bf_[4];
#pragma unroll
    for (int mt = 0; mt < 2; ++mt) {
      const int r = wr * 32 + mt * 16 + ln15;
      af[mt] = *(const bf16x8*)((const char*)Ab[cur] + r * 64 + (g ^ ((r >> 1) & 3)) * 16);
    }
#pragma unroll
    for (int nt = 0; nt < 4; ++nt) {
      const int c2 = wc * 64 + nt * 16 + ln15;
      bf_[nt] = *(const bf16x8*)((const char*)Bb[cur] + c2 * 64 + (g ^ ((c2 >> 1) & 3)) * 16);
    }
#pragma unroll
    for (int mt = 0; mt < 2; ++mt)
#pragma unroll
      for (int nt = 0; nt < 4; ++nt)
        acc[mt][nt] = __builtin_amdgcn_mfma_f32_16x16x32_bf16(af[mt], bf_[nt], acc[mt][nt], 0, 0, 0);
    if (kt < 31) writeA(nb);  // cvt+ds_write overlaps in-flight B gloads
    __syncthreads();
    cur = nb;
  }

  // epilogue: +b1, swish, store bf16 into Hp panel-major (linear 64B chunks)
  float bv[4];
#pragma unroll
  for (int nt = 0; nt < 4; ++nt)
    bv[nt] = b1[e * UDIM + Nt * 128 + wc * 64 + nt * 16 + ln15];
#pragma unroll
  for (int mt = 0; mt < 2; ++mt) {
#pragma unroll
    for (int nt = 0; nt < 4; ++nt) {
      const int colg = Nt * 128 + wc * 64 + nt * 16 + ln15;
      unsigned short* hp = Hp + ((size_t)(Mt * 16 + (colg >> 5)) * 64) * 32 + (colg & 31);
#pragma unroll
      for (int r = 0; r < 4; ++r) {
        const int row = wr * 32 + mt * 16 + g * 4 + r;
        const float a = acc[mt][nt][r] + bv[nt];
        hp[(size_t)row * 32] = f2bf(a / (1.f + __expf(-a)));
      }
    }
  }
}

// ---- GEMM2: Z = H @ proj[e]; epilogue sigmoid->RBF->ctrl->scale->scatter ---

__global__ __launch_bounds__(256) void k_gemm2(
    const unsigned short* __restrict__ Hp, const unsigned short* __restrict__ projp,
    const float* __restrict__ ctrl, const float* __restrict__ scaling,
    const int* __restrict__ perm_p, const int* __restrict__ tile_expert,
    const int* __restrict__ tile_rowlim, float* __restrict__ out) {
  __shared__ __align__(16) short Ab[2][64 * 32];
  __shared__ __align__(16) short Bb[2][128 * 32];
  __shared__ int tok_s[64];

  const int Mt = blockIdx.x;
  const int e = tile_expert[Mt];
  if (e < 0) return;
  const int Nt = blockIdx.y;  // 0..3
  const int rowlim = tile_rowlim[Mt];

  const int t = threadIdx.x;
  const int w = t >> 6, wr = w >> 1, wc = w & 1;
  const int lane = t & 63, ln15 = lane & 15, g = lane >> 4;

  if (t < 64) tok_s[t] = perm_p[Mt * 64 + (t < rowlim ? t : 0)];
  __syncthreads();

  const int srow = t >> 2;
  const int sh = (t & 3) ^ ((srow >> 1) & 3);
  const unsigned short* Apan = Hp + ((size_t)Mt * 16 * 64) * 32;
  const unsigned short* Bpan = projp + ((size_t)e * 16 * UDIM + Nt * 128) * 32;

  auto stage = [&](int kt, int buf) {
    gload16(Apan + (size_t)kt * 64 * 32 + srow * 32 + sh * 8,
            (char*)Ab[buf] + (t & ~63) * 16);
#pragma unroll
    for (int j = 0; j < 2; ++j) {
      const int c = t + j * 256;
      const int u2 = c >> 2, h = (c & 3) ^ ((u2 >> 1) & 3);
      gload16(Bpan + (size_t)kt * UDIM * 32 + u2 * 32 + h * 8,
              (char*)Bb[buf] + (c & ~63) * 16);
    }
  };

  f32x4 acc[2][4];
  const f32x4 z4 = {0.f, 0.f, 0.f, 0.f};
#pragma unroll
  for (int a = 0; a < 2; ++a)
#pragma unroll
    for (int b = 0; b < 4; ++b) acc[a][b] = z4;

  stage(0, 0);
  __syncthreads();
  int cur = 0;
  for (int kt = 0; kt < 16; ++kt) {
    const int nb = cur ^ 1;
    if (kt < 15) stage(kt + 1, nb);
    bf16x8 af[2], bf_[4];
#pragma unroll
    for (int mt = 0; mt < 2; ++mt) {
      const int r = wr * 32 + mt * 16 + ln15;
      af[mt] = *(const bf16x8*)((const char*)Ab[cur] + r * 64 + (g ^ ((r >> 1) & 3)) * 16);
    }
#pragma unroll
    for (int nt = 0; nt < 4; ++nt) {
      const int c2 = wc * 64 + nt * 16 + ln15;
      bf_[nt] = *(const bf16x8*)((const char*)Bb[cur] + c2 * 64 + (g ^ ((c2 >> 1) & 3)) * 16);
    }
#pragma unroll
    for (int mt = 0; mt < 2; ++mt)
#pragma unroll
      for (int nt = 0; nt < 4; ++nt)
        acc[mt][nt] = __builtin_amdgcn_mfma_f32_16x16x32_bf16(af[mt], bf_[nt], acc[mt][nt], 0, 0, 0);
    __syncthreads();
    cur = nb;
  }

  // epilogue: sigmoid -> gaussian RBF basis -> ctrl dot -> scale -> scatter
  const float kInv7 = 0.14285714285714285f;  // knots = b/7
  float cv[4][8], sc[4];
#pragma unroll
  for (int nt = 0; nt < 4; ++nt) {
    const int colg = Nt * 128 + wc * 64 + nt * 16 + ln15;
    sc[nt] = scaling[e * UDIM + colg];
#pragma unroll
    for (int b = 0; b < 8; ++b) cv[nt][b] = ctrl[((size_t)e * 8 + b) * UDIM + colg];
  }
#pragma unroll
  for (int mt = 0; mt < 2; ++mt) {
#pragma unroll
    for (int r = 0; r < 4; ++r) {
      const int row = wr * 32 + mt * 16 + g * 4 + r;
      if (row < rowlim) {
        const int tok = tok_s[row];
#pragma unroll
        for (int nt = 0; nt < 4; ++nt) {
          const int colg = Nt * 128 + wc * 64 + nt * 16 + ln15;
          const float z = acc[mt][nt][r];
          const float xn = 1.f / (1.f + __expf(-z));
          float s = 0.f, dc = 0.f;
#pragma unroll
          for (int b = 0; b < 8; ++b) {
            const float d = xn - (float)b * kInv7;
            const float bas = __expf(-32.f * d * d);  // exp(-d^2/(2*(1/8)^2))
            s += bas;
            dc = fmaf(bas, cv[nt][b], dc);
          }
          out[(size_t)tok * UDIM + colg] = dc / (s + 1e-6f) * sc[nt];
        }
      }
    }
  }
}

// ---- host launch -----------------------------------------------------------

extern "C" void kernel_launch(void* const* d_in, const int* in_sizes, int n_in,
                              void* d_out, int out_size, void* d_ws, size_t ws_size,
                              hipStream_t stream) {
  const float* x       = (const float*)d_in[0];
  const float* W1      = (const float*)d_in[1];
  const float* b1      = (const float*)d_in[2];
  const float* proj    = (const float*)d_in[3];
  const float* ctrl    = (const float*)d_in[4];
  const float* scaling = (const float*)d_in[5];
  const float* Wg      = (const float*)d_in[6];
  const float* bg      = (const float*)d_in[7];
  float* out = (float*)d_out;
  char* ws = (char*)d_ws;

  // workspace layout (~21 MB)
  int* eidx        = (int*)(ws + 0);                 // 32KB
  int* perm_p      = (int*)(ws + 32768);             // 8704*4
  int* counts      = (int*)(ws + 69632);             // 32B
  int* cursors     = (int*)(ws + 69632 + 32);        // 32B
  int* tile_expert = (int*)(ws + 69632 + 64);        // 544B
  int* tile_rowlim = (int*)(ws + 69632 + 640);       // 544B
  unsigned short* W1p   = (unsigned short*)(ws + 131072);                       // 8MB
  unsigned short* projp = (unsigned short*)(ws + 131072 + 8388608);             // 4MB
  unsigned short* Hp    = (unsigned short*)(ws + 131072 + 8388608 + 4194304);   // 8.9MB

  hipMemsetAsync(counts, 0, 32, stream);

  k_prep<<<NTOK / 4, 256, 0, stream>>>(x, Wg, bg, eidx, counts);
  k_pack<<<dim3(UDIM / 64, DDIM / 64, 16), 256, 0, stream>>>(W1, proj, W1p, projp);
  k_scan<<<1, 256, 0, stream>>>(counts, cursors, tile_expert, tile_rowlim);
  k_scatter<<<NTOK / 256, 256, 0, stream>>>(eidx, cursors, perm_p);
  k_gemm1<<<dim3(MT_MAX, UDIM / 128), 256, 0, stream>>>(x, W1p, b1, perm_p,
                                                        tile_expert, tile_rowlim, Hp);
  k_gemm2<<<dim3(MT_MAX, UDIM / 128), 256, 0, stream>>>(Hp, projp, ctrl, scaling, perm_p,
                                                        tile_expert, tile_rowlim, out);
}

// Round 7
// 84.948 us; speedup vs baseline: 2.8940x; 2.3749x over previous
//
#include <hip/hip_runtime.h>
#include <hip/hip_bf16.h>
#include <stdint.h>

// Problem constants: N=8192 tokens, D=1024, U=512, E=8, B=8 bases.
#define NTOK 8192
#define DDIM 1024
#define UDIM 512
#define NEXP 8
#define MT_MAX 136   // max padded 64-row M-tiles: 8192/64 + 7 partials + slack

typedef __attribute__((ext_vector_type(8))) short bf16x8;
typedef __attribute__((ext_vector_type(4))) float f32x4;

// ---- helpers ---------------------------------------------------------------

__device__ __forceinline__ unsigned short f2bf(float f) {
  unsigned int u = __float_as_uint(f);
  u += 0x7FFFu + ((u >> 16) & 1u);
  return (unsigned short)(u >> 16);
}

__device__ __forceinline__ void gload16(const void* g, void* lds) {
  // async global->LDS, 16B/lane; LDS dest = wave-uniform base + lane*16 (HW rule)
  __builtin_amdgcn_global_load_lds(
      (__attribute__((address_space(1))) void*)(uintptr_t)g,
      (__attribute__((address_space(3))) void*)(uint32_t)(uintptr_t)lds,
      16, 0, 0);
}

// ---- gating: WgT in LDS, coalesced x, f32 argmax. NO ATOMICS ----------------
// Block = 256 thr = 4 token-waves. Lane l covers d in {c*256 + l*4 .. +3}.

__global__ __launch_bounds__(256) void k_prep(const float* __restrict__ x,
                                              const float* __restrict__ Wg,
                                              const float* __restrict__ bg,
                                              int* __restrict__ eidx) {
  __shared__ float WgT[8][1040];  // transposed gate weights, padded row (33.3KB)
  const int t = threadIdx.x;
  // stage: Wg[1024][8] -> WgT[e][d]; global reads perfectly coalesced
#pragma unroll
  for (int r = 0; r < 32; ++r)
    WgT[t & 7][r * 32 + (t >> 3)] = Wg[r * 256 + t];
  __syncthreads();

  const int lane = t & 63;
  const int n = (blockIdx.x << 2) + (t >> 6);
  const float* xr = x + (size_t)n * DDIM;
  float acc[8] = {0.f, 0.f, 0.f, 0.f, 0.f, 0.f, 0.f, 0.f};
#pragma unroll
  for (int c = 0; c < 4; ++c) {
    const float4 xv = *(const float4*)(xr + c * 256 + lane * 4);
#pragma unroll
    for (int e = 0; e < 8; ++e) {
      const float4 wv = *(const float4*)(&WgT[e][c * 256 + lane * 4]);
      acc[e] = fmaf(xv.x, wv.x, acc[e]);
      acc[e] = fmaf(xv.y, wv.y, acc[e]);
      acc[e] = fmaf(xv.z, wv.z, acc[e]);
      acc[e] = fmaf(xv.w, wv.w, acc[e]);
    }
  }
#pragma unroll
  for (int e = 0; e < 8; ++e) {
#pragma unroll
    for (int o = 32; o > 0; o >>= 1) acc[e] += __shfl_xor(acc[e], o, 64);
  }
  if (lane == 0) {
    int best = 0;
    float bv = acc[0] + bg[0];
#pragma unroll
    for (int e2 = 1; e2 < 8; ++e2) {
      const float v = acc[e2] + bg[e2];
      if (v > bv) { bv = v; best = e2; }  // strict > = np.argmax first-index ties
    }
    eidx[n] = best;
  }
}

// ---- pack weights: src[R][C] f32 -> panels [R/32 kt][C][32] bf16 (linear) ---
// z<8: W1 expert z (R=1024); z>=8: proj expert z-8 (R=512). C=512 for both.

__global__ void k_pack(const float* __restrict__ W1, const float* __restrict__ proj,
                       unsigned short* __restrict__ W1p, unsigned short* __restrict__ projp) {
  __shared__ float tile[64][65];
  const int z = blockIdx.z;
  const int R = (z < 8) ? DDIM : UDIM;
  const int r0 = blockIdx.y << 6;
  if (r0 >= R) return;
  const int c0 = blockIdx.x << 6;
  const float* src = (z < 8) ? (W1 + (size_t)z * DDIM * UDIM)
                             : (proj + (size_t)(z - 8) * UDIM * UDIM);
  unsigned short* dst = (z < 8) ? (W1p + (size_t)z * DDIM * UDIM)
                                : (projp + (size_t)(z - 8) * UDIM * UDIM);
  const int t = threadIdx.x;
#pragma unroll
  for (int i = 0; i < 4; ++i) {
    const int ri = (t >> 4) + i * 16;
    const int ci = (t & 15) * 4;
    const float4 v = *(const float4*)(src + (size_t)(r0 + ri) * UDIM + c0 + ci);
    tile[ri][ci] = v.x; tile[ri][ci + 1] = v.y; tile[ri][ci + 2] = v.z; tile[ri][ci + 3] = v.w;
  }
  __syncthreads();
  const int cc = t >> 2, ch = t & 3;
#pragma unroll
  for (int j = 0; j < 2; ++j) {
    const int kt = (r0 >> 5) + j;
    union { bf16x8 v; unsigned short u[8]; } pk;
#pragma unroll
    for (int q = 0; q < 8; ++q) pk.u[q] = f2bf(tile[j * 32 + ch * 8 + q][cc]);
    *(bf16x8*)(dst + ((size_t)kt * UDIM + c0 + cc) * 32 + ch * 8) = pk.v;
  }
}

// ---- sort: histogram + scan + stable scatter + tile maps, ZERO atomics -----
// 1 block x 1024 threads; thread t owns tokens [t*8, t*8+8).

__global__ __launch_bounds__(1024) void k_sort(const int* __restrict__ eidx,
                                               int* __restrict__ perm_p,
                                               int* __restrict__ tile_expert,
                                               int* __restrict__ tile_rowlim) {
  __shared__ int hist[8][1024];   // per-bin per-thread counts -> inclusive prefix
  __shared__ int tbase[9];        // tile base per expert
  const int t = threadIdx.x;

  int my[8], c[8] = {0, 0, 0, 0, 0, 0, 0, 0};
#pragma unroll
  for (int i = 0; i < 8; ++i) {
    my[i] = eidx[t * 8 + i];
#pragma unroll
    for (int b = 0; b < 8; ++b) c[b] += (my[i] == b);
  }
#pragma unroll
  for (int b = 0; b < 8; ++b) hist[b][t] = c[b];
  __syncthreads();

  // inclusive Hillis-Steele scan per bin across 1024 threads
  for (int off = 1; off < 1024; off <<= 1) {
    int v[8];
#pragma unroll
    for (int b = 0; b < 8; ++b) v[b] = (t >= off) ? hist[b][t - off] : 0;
    __syncthreads();
#pragma unroll
    for (int b = 0; b < 8; ++b) hist[b][t] += v[b];
    __syncthreads();
  }

  if (t == 0) {
    int run = 0;
    for (int e = 0; e < 8; ++e) { tbase[e] = run; run += (hist[e][1023] + 63) >> 6; }
    tbase[8] = run;
  }
  __syncthreads();

  // stable scatter: token base of expert segment + exclusive prefix
  int base[8];
#pragma unroll
  for (int b = 0; b < 8; ++b) base[b] = (tbase[b] << 6) + hist[b][t] - c[b];
#pragma unroll
  for (int b = 0; b < 8; ++b) {
    int p = base[b];
#pragma unroll
    for (int i = 0; i < 8; ++i)
      if (my[i] == b) perm_p[p++] = t * 8 + i;
  }

  // tile maps
  if (t < MT_MAX) {
    int e = -1, rl = 0;
#pragma unroll
    for (int q = 0; q < 8; ++q) {
      if (t >= tbase[q] && t < tbase[q + 1]) {
        e = q;
        const int r = hist[q][1023] - (t - tbase[q]) * 64;
        rl = r < 64 ? r : 64;
      }
    }
    tile_expert[t] = e;
    tile_rowlim[t] = rl;
  }
}

// ---- GEMM1: H = swish(x[tok] @ W1[e] + b1[e]) -> Hp panels bf16 ------------
// 64x128 tile, BK=32, 4 waves (2x2, each 32x64 out), 24KB LDS dbuf.

__global__ __launch_bounds__(256) void k_gemm1(
    const float* __restrict__ x, const unsigned short* __restrict__ W1p,
    const float* __restrict__ b1, const int* __restrict__ perm_p,
    const int* __restrict__ tile_expert, const int* __restrict__ tile_rowlim,
    unsigned short* __restrict__ Hp) {
  __shared__ __align__(16) short Ab[2][64 * 32];
  __shared__ __align__(16) short Bb[2][128 * 32];
  __shared__ int rows_s[64];

  const int Mt = blockIdx.x;
  const int e = tile_expert[Mt];
  if (e < 0) return;
  const int Nt = blockIdx.y;  // 0..3 (128-col slices)
  const int rowlim = tile_rowlim[Mt];

  const int t = threadIdx.x;
  const int w = t >> 6, wr = w >> 1, wc = w & 1;
  const int lane = t & 63, ln15 = lane & 15, g = lane >> 4;

  if (t < 64) rows_s[t] = perm_p[Mt * 64 + (t < rowlim ? t : 0)];
  __syncthreads();

  const int arow = t >> 2;
  const int ah = (t & 3) ^ ((arow >> 1) & 3);  // pre-swizzled source chunk (pairs read-side XOR)
  const float* xrow = x + (size_t)rows_s[arow] * DDIM + ah * 8;
  const unsigned short* Bpan = W1p + ((size_t)e * 32 * UDIM + Nt * 128) * 32;

  float4 av0, av1;
  auto issueA = [&](int kt) {
    const float* s = xrow + kt * 32;
    av0 = *(const float4*)s; av1 = *(const float4*)(s + 4);
  };
  auto writeA = [&](int buf) {
    union { bf16x8 v; unsigned short u[8]; } pk;
    pk.u[0] = f2bf(av0.x); pk.u[1] = f2bf(av0.y); pk.u[2] = f2bf(av0.z); pk.u[3] = f2bf(av0.w);
    pk.u[4] = f2bf(av1.x); pk.u[5] = f2bf(av1.y); pk.u[6] = f2bf(av1.z); pk.u[7] = f2bf(av1.w);
    *(bf16x8*)((char*)Ab[buf] + t * 16) = pk.v;
  };
  auto issueB = [&](int kt, int buf) {
#pragma unroll
    for (int j = 0; j < 2; ++j) {
      const int c = t + j * 256;
      const int u2 = c >> 2, h = (c & 3) ^ ((u2 >> 1) & 3);
      gload16(Bpan + (size_t)kt * UDIM * 32 + u2 * 32 + h * 8,
              (char*)Bb[buf] + (c & ~63) * 16);
    }
  };

  f32x4 acc[2][4];
  const f32x4 z4 = {0.f, 0.f, 0.f, 0.f};
#pragma unroll
  for (int a = 0; a < 2; ++a)
#pragma unroll
    for (int b = 0; b < 4; ++b) acc[a][b] = z4;

  issueA(0); issueB(0, 0); writeA(0);
  __syncthreads();
  int cur = 0;
  for (int kt = 0; kt < 32; ++kt) {
    const int nb = cur ^ 1;
    if (kt < 31) { issueA(kt + 1); issueB(kt + 1, nb); }
    bf16x8 af[2], bf_[4];
#pragma unroll
    for (int mt = 0; mt < 2; ++mt) {
      const int r = wr * 32 + mt * 16 + ln15;
      af[mt] = *(const bf16x8*)((const char*)Ab[cur] + r * 64 + (g ^ ((r >> 1) & 3)) * 16);
    }
#pragma unroll
    for (int nt = 0; nt < 4; ++nt) {
      const int c2 = wc * 64 + nt * 16 + ln15;
      bf_[nt] = *(const bf16x8*)((const char*)Bb[cur] + c2 * 64 + (g ^ ((c2 >> 1) & 3)) * 16);
    }
#pragma unroll
    for (int mt = 0; mt < 2; ++mt)
#pragma unroll
      for (int nt = 0; nt < 4; ++nt)
        acc[mt][nt] = __builtin_amdgcn_mfma_f32_16x16x32_bf16(af[mt], bf_[nt], acc[mt][nt], 0, 0, 0);
    if (kt < 31) writeA(nb);  // cvt+ds_write overlaps in-flight B gloads
    __syncthreads();
    cur = nb;
  }

  // epilogue: +b1, swish, store bf16 into Hp panel-major (linear 64B chunks)
  float bv[4];
#pragma unroll
  for (int nt = 0; nt < 4; ++nt)
    bv[nt] = b1[e * UDIM + Nt * 128 + wc * 64 + nt * 16 + ln15];
#pragma unroll
  for (int mt = 0; mt < 2; ++mt) {
#pragma unroll
    for (int nt = 0; nt < 4; ++nt) {
      const int colg = Nt * 128 + wc * 64 + nt * 16 + ln15;
      unsigned short* hp = Hp + ((size_t)(Mt * 16 + (colg >> 5)) * 64) * 32 + (colg & 31);
#pragma unroll
      for (int r = 0; r < 4; ++r) {
        const int row = wr * 32 + mt * 16 + g * 4 + r;
        const float a = acc[mt][nt][r] + bv[nt];
        hp[(size_t)row * 32] = f2bf(a / (1.f + __expf(-a)));
      }
    }
  }
}

// ---- GEMM2: Z = H @ proj[e]; epilogue sigmoid->RBF->ctrl->scale->scatter ---

__global__ __launch_bounds__(256) void k_gemm2(
    const unsigned short* __restrict__ Hp, const unsigned short* __restrict__ projp,
    const float* __restrict__ ctrl, const float* __restrict__ scaling,
    const int* __restrict__ perm_p, const int* __restrict__ tile_expert,
    const int* __restrict__ tile_rowlim, float* __restrict__ out) {
  __shared__ __align__(16) short Ab[2][64 * 32];
  __shared__ __align__(16) short Bb[2][128 * 32];
  __shared__ int tok_s[64];

  const int Mt = blockIdx.x;
  const int e = tile_expert[Mt];
  if (e < 0) return;
  const int Nt = blockIdx.y;  // 0..3
  const int rowlim = tile_rowlim[Mt];

  const int t = threadIdx.x;
  const int w = t >> 6, wr = w >> 1, wc = w & 1;
  const int lane = t & 63, ln15 = lane & 15, g = lane >> 4;

  if (t < 64) tok_s[t] = perm_p[Mt * 64 + (t < rowlim ? t : 0)];
  __syncthreads();

  const int srow = t >> 2;
  const int sh = (t & 3) ^ ((srow >> 1) & 3);
  const unsigned short* Apan = Hp + ((size_t)Mt * 16 * 64) * 32;
  const unsigned short* Bpan = projp + ((size_t)e * 16 * UDIM + Nt * 128) * 32;

  auto stage = [&](int kt, int buf) {
    gload16(Apan + (size_t)kt * 64 * 32 + srow * 32 + sh * 8,
            (char*)Ab[buf] + (t & ~63) * 16);
#pragma unroll
    for (int j = 0; j < 2; ++j) {
      const int c = t + j * 256;
      const int u2 = c >> 2, h = (c & 3) ^ ((u2 >> 1) & 3);
      gload16(Bpan + (size_t)kt * UDIM * 32 + u2 * 32 + h * 8,
              (char*)Bb[buf] + (c & ~63) * 16);
    }
  };

  f32x4 acc[2][4];
  const f32x4 z4 = {0.f, 0.f, 0.f, 0.f};
#pragma unroll
  for (int a = 0; a < 2; ++a)
#pragma unroll
    for (int b = 0; b < 4; ++b) acc[a][b] = z4;

  stage(0, 0);
  __syncthreads();
  int cur = 0;
  for (int kt = 0; kt < 16; ++kt) {
    const int nb = cur ^ 1;
    if (kt < 15) stage(kt + 1, nb);
    bf16x8 af[2], bf_[4];
#pragma unroll
    for (int mt = 0; mt < 2; ++mt) {
      const int r = wr * 32 + mt * 16 + ln15;
      af[mt] = *(const bf16x8*)((const char*)Ab[cur] + r * 64 + (g ^ ((r >> 1) & 3)) * 16);
    }
#pragma unroll
    for (int nt = 0; nt < 4; ++nt) {
      const int c2 = wc * 64 + nt * 16 + ln15;
      bf_[nt] = *(const bf16x8*)((const char*)Bb[cur] + c2 * 64 + (g ^ ((c2 >> 1) & 3)) * 16);
    }
#pragma unroll
    for (int mt = 0; mt < 2; ++mt)
#pragma unroll
      for (int nt = 0; nt < 4; ++nt)
        acc[mt][nt] = __builtin_amdgcn_mfma_f32_16x16x32_bf16(af[mt], bf_[nt], acc[mt][nt], 0, 0, 0);
    __syncthreads();
    cur = nb;
  }

  // epilogue: sigmoid -> gaussian RBF basis -> ctrl dot -> scale -> scatter
  const float kInv7 = 0.14285714285714285f;  // knots = b/7
  float cv[4][8], sc[4];
#pragma unroll
  for (int nt = 0; nt < 4; ++nt) {
    const int colg = Nt * 128 + wc * 64 + nt * 16 + ln15;
    sc[nt] = scaling[e * UDIM + colg];
#pragma unroll
    for (int b = 0; b < 8; ++b) cv[nt][b] = ctrl[((size_t)e * 8 + b) * UDIM + colg];
  }
#pragma unroll
  for (int mt = 0; mt < 2; ++mt) {
#pragma unroll
    for (int r = 0; r < 4; ++r) {
      const int row = wr * 32 + mt * 16 + g * 4 + r;
      if (row < rowlim) {
        const int tok = tok_s[row];
#pragma unroll
        for (int nt = 0; nt < 4; ++nt) {
          const int colg = Nt * 128 + wc * 64 + nt * 16 + ln15;
          const float z = acc[mt][nt][r];
          const float xn = 1.f / (1.f + __expf(-z));
          float s = 0.f, dc = 0.f;
#pragma unroll
          for (int b = 0; b < 8; ++b) {
            const float d = xn - (float)b * kInv7;
            const float bas = __expf(-32.f * d * d);  // exp(-d^2/(2*(1/8)^2))
            s += bas;
            dc = fmaf(bas, cv[nt][b], dc);
          }
          out[(size_t)tok * UDIM + colg] = dc / (s + 1e-6f) * sc[nt];
        }
      }
    }
  }
}

// ---- host launch -----------------------------------------------------------

extern "C" void kernel_launch(void* const* d_in, const int* in_sizes, int n_in,
                              void* d_out, int out_size, void* d_ws, size_t ws_size,
                              hipStream_t stream) {
  const float* x       = (const float*)d_in[0];
  const float* W1      = (const float*)d_in[1];
  const float* b1      = (const float*)d_in[2];
  const float* proj    = (const float*)d_in[3];
  const float* ctrl    = (const float*)d_in[4];
  const float* scaling = (const float*)d_in[5];
  const float* Wg      = (const float*)d_in[6];
  const float* bg      = (const float*)d_in[7];
  float* out = (float*)d_out;
  char* ws = (char*)d_ws;

  // workspace layout (~21 MB)
  int* eidx        = (int*)(ws + 0);                 // 32KB
  int* perm_p      = (int*)(ws + 32768);             // 8704*4
  int* tile_expert = (int*)(ws + 69632 + 64);        // 544B
  int* tile_rowlim = (int*)(ws + 69632 + 640);       // 544B
  unsigned short* W1p   = (unsigned short*)(ws + 131072);                       // 8MB
  unsigned short* projp = (unsigned short*)(ws + 131072 + 8388608);             // 4MB
  unsigned short* Hp    = (unsigned short*)(ws + 131072 + 8388608 + 4194304);   // 8.9MB

  k_prep<<<NTOK / 4, 256, 0, stream>>>(x, Wg, bg, eidx);
  k_pack<<<dim3(UDIM / 64, DDIM / 64, 16), 256, 0, stream>>>(W1, proj, W1p, projp);
  k_sort<<<1, 1024, 0, stream>>>(eidx, perm_p, tile_expert, tile_rowlim);
  k_gemm1<<<dim3(MT_MAX, UDIM / 128), 256, 0, stream>>>(x, W1p, b1, perm_p,
                                                        tile_expert, tile_rowlim, Hp);
  k_gemm2<<<dim3(MT_MAX, UDIM / 128), 256, 0, stream>>>(Hp, projp, ctrl, scaling, perm_p,
                                                        tile_expert, tile_rowlim, out);
}

// Round 8
// 74.115 us; speedup vs baseline: 3.3170x; 1.1462x over previous
//
#include <hip/hip_runtime.h>
#include <hip/hip_bf16.h>
#include <stdint.h>

// Problem constants: N=8192 tokens, D=1024, U=512, E=8, B=8 bases.
#define NTOK 8192
#define DDIM 1024
#define UDIM 512
#define NEXP 8
#define MT_MAX 136   // max padded 64-row M-tiles: 8192/64 + 7 partials + slack

typedef __attribute__((ext_vector_type(8))) short bf16x8;
typedef __attribute__((ext_vector_type(4))) float f32x4;

// ---- helpers ---------------------------------------------------------------

__device__ __forceinline__ unsigned short f2bf(float f) {
  unsigned int u = __float_as_uint(f);
  u += 0x7FFFu + ((u >> 16) & 1u);
  return (unsigned short)(u >> 16);
}

__device__ __forceinline__ void gload16(const void* g, void* lds) {
  // async global->LDS, 16B/lane; LDS dest = wave-uniform base + lane*16 (HW rule)
  __builtin_amdgcn_global_load_lds(
      (__attribute__((address_space(1))) void*)(uintptr_t)g,
      (__attribute__((address_space(3))) void*)(uint32_t)(uintptr_t)lds,
      16, 0, 0);
}

// ---- gating: WgT in LDS, coalesced x, f32 argmax. NO ATOMICS ----------------

__global__ __launch_bounds__(256) void k_prep(const float* __restrict__ x,
                                              const float* __restrict__ Wg,
                                              const float* __restrict__ bg,
                                              int* __restrict__ eidx) {
  __shared__ float WgT[8][1040];  // transposed gate weights, padded row (33.3KB)
  const int t = threadIdx.x;
#pragma unroll
  for (int r = 0; r < 32; ++r)
    WgT[t & 7][r * 32 + (t >> 3)] = Wg[r * 256 + t];
  __syncthreads();

  const int lane = t & 63;
  const int n = (blockIdx.x << 2) + (t >> 6);
  const float* xr = x + (size_t)n * DDIM;
  float acc[8] = {0.f, 0.f, 0.f, 0.f, 0.f, 0.f, 0.f, 0.f};
#pragma unroll
  for (int c = 0; c < 4; ++c) {
    const float4 xv = *(const float4*)(xr + c * 256 + lane * 4);
#pragma unroll
    for (int e = 0; e < 8; ++e) {
      const float4 wv = *(const float4*)(&WgT[e][c * 256 + lane * 4]);
      acc[e] = fmaf(xv.x, wv.x, acc[e]);
      acc[e] = fmaf(xv.y, wv.y, acc[e]);
      acc[e] = fmaf(xv.z, wv.z, acc[e]);
      acc[e] = fmaf(xv.w, wv.w, acc[e]);
    }
  }
#pragma unroll
  for (int e = 0; e < 8; ++e) {
#pragma unroll
    for (int o = 32; o > 0; o >>= 1) acc[e] += __shfl_xor(acc[e], o, 64);
  }
  if (lane == 0) {
    int best = 0;
    float bv = acc[0] + bg[0];
#pragma unroll
    for (int e2 = 1; e2 < 8; ++e2) {
      const float v = acc[e2] + bg[e2];
      if (v > bv) { bv = v; best = e2; }  // strict > = np.argmax first-index ties
    }
    eidx[n] = best;
  }
}

// ---- pack weights: src[R][C] f32 -> panels [R/32 kt][C][32] bf16 (linear) ---

__global__ void k_pack(const float* __restrict__ W1, const float* __restrict__ proj,
                       unsigned short* __restrict__ W1p, unsigned short* __restrict__ projp) {
  __shared__ float tile[64][65];
  const int z = blockIdx.z;
  const int R = (z < 8) ? DDIM : UDIM;
  const int r0 = blockIdx.y << 6;
  if (r0 >= R) return;
  const int c0 = blockIdx.x << 6;
  const float* src = (z < 8) ? (W1 + (size_t)z * DDIM * UDIM)
                             : (proj + (size_t)(z - 8) * UDIM * UDIM);
  unsigned short* dst = (z < 8) ? (W1p + (size_t)z * DDIM * UDIM)
                                : (projp + (size_t)(z - 8) * UDIM * UDIM);
  const int t = threadIdx.x;
#pragma unroll
  for (int i = 0; i < 4; ++i) {
    const int ri = (t >> 4) + i * 16;
    const int ci = (t & 15) * 4;
    const float4 v = *(const float4*)(src + (size_t)(r0 + ri) * UDIM + c0 + ci);
    tile[ri][ci] = v.x; tile[ri][ci + 1] = v.y; tile[ri][ci + 2] = v.z; tile[ri][ci + 3] = v.w;
  }
  __syncthreads();
  const int cc = t >> 2, ch = t & 3;
#pragma unroll
  for (int j = 0; j < 2; ++j) {
    const int kt = (r0 >> 5) + j;
    union { bf16x8 v; unsigned short u[8]; } pk;
#pragma unroll
    for (int q = 0; q < 8; ++q) pk.u[q] = f2bf(tile[j * 32 + ch * 8 + q][cc]);
    *(bf16x8*)(dst + ((size_t)kt * UDIM + c0 + cc) * 32 + ch * 8) = pk.v;
  }
}

// ---- sort: histogram + scan + stable scatter + tile maps, ZERO atomics -----

__global__ __launch_bounds__(1024) void k_sort(const int* __restrict__ eidx,
                                               int* __restrict__ perm_p,
                                               int* __restrict__ tile_expert,
                                               int* __restrict__ tile_rowlim) {
  __shared__ int hist[8][1024];
  __shared__ int tbase[9];
  const int t = threadIdx.x;

  int my[8], c[8] = {0, 0, 0, 0, 0, 0, 0, 0};
#pragma unroll
  for (int i = 0; i < 8; ++i) {
    my[i] = eidx[t * 8 + i];
#pragma unroll
    for (int b = 0; b < 8; ++b) c[b] += (my[i] == b);
  }
#pragma unroll
  for (int b = 0; b < 8; ++b) hist[b][t] = c[b];
  __syncthreads();

  for (int off = 1; off < 1024; off <<= 1) {
    int v[8];
#pragma unroll
    for (int b = 0; b < 8; ++b) v[b] = (t >= off) ? hist[b][t - off] : 0;
    __syncthreads();
#pragma unroll
    for (int b = 0; b < 8; ++b) hist[b][t] += v[b];
    __syncthreads();
  }

  if (t == 0) {
    int run = 0;
    for (int e = 0; e < 8; ++e) { tbase[e] = run; run += (hist[e][1023] + 63) >> 6; }
    tbase[8] = run;
  }
  __syncthreads();

  int base[8];
#pragma unroll
  for (int b = 0; b < 8; ++b) base[b] = (tbase[b] << 6) + hist[b][t] - c[b];
#pragma unroll
  for (int b = 0; b < 8; ++b) {
    int p = base[b];
#pragma unroll
    for (int i = 0; i < 8; ++i)
      if (my[i] == b) perm_p[p++] = t * 8 + i;
  }

  if (t < MT_MAX) {
    int e = -1, rl = 0;
#pragma unroll
    for (int q = 0; q < 8; ++q) {
      if (t >= tbase[q] && t < tbase[q + 1]) {
        e = q;
        const int r = hist[q][1023] - (t - tbase[q]) * 64;
        rl = r < 64 ? r : 64;
      }
    }
    tile_expert[t] = e;
    tile_rowlim[t] = rl;
  }
}

// ---- GEMM1: H = swish(x[tok] @ W1[e] + b1[e]) -> Hp panels bf16 ------------
// 64x128 tile, BK=32, 4 waves (2x2, each 32x64 out), 24KB LDS dbuf.

__global__ __launch_bounds__(256) void k_gemm1(
    const float* __restrict__ x, const unsigned short* __restrict__ W1p,
    const float* __restrict__ b1, const int* __restrict__ perm_p,
    const int* __restrict__ tile_expert, const int* __restrict__ tile_rowlim,
    unsigned short* __restrict__ Hp) {
  __shared__ __align__(16) short Ab[2][64 * 32];
  __shared__ __align__(16) short Bb[2][128 * 32];
  __shared__ int rows_s[64];

  const int Mt = blockIdx.x;
  const int e = tile_expert[Mt];
  if (e < 0) return;
  const int Nt = blockIdx.y;  // 0..3 (128-col slices)
  const int rowlim = tile_rowlim[Mt];

  const int t = threadIdx.x;
  const int w = t >> 6, wr = w >> 1, wc = w & 1;
  const int lane = t & 63, ln15 = lane & 15, g = lane >> 4;

  if (t < 64) rows_s[t] = perm_p[Mt * 64 + (t < rowlim ? t : 0)];
  __syncthreads();

  const int arow = t >> 2;
  const int ah = (t & 3) ^ ((arow >> 1) & 3);
  const float* xrow = x + (size_t)rows_s[arow] * DDIM + ah * 8;
  const unsigned short* Bpan = W1p + ((size_t)e * 32 * UDIM + Nt * 128) * 32;

  float4 av0, av1;
  auto issueA = [&](int kt) {
    const float* s = xrow + kt * 32;
    av0 = *(const float4*)s; av1 = *(const float4*)(s + 4);
  };
  auto writeA = [&](int buf) {
    union { bf16x8 v; unsigned short u[8]; } pk;
    pk.u[0] = f2bf(av0.x); pk.u[1] = f2bf(av0.y); pk.u[2] = f2bf(av0.z); pk.u[3] = f2bf(av0.w);
    pk.u[4] = f2bf(av1.x); pk.u[5] = f2bf(av1.y); pk.u[6] = f2bf(av1.z); pk.u[7] = f2bf(av1.w);
    *(bf16x8*)((char*)Ab[buf] + t * 16) = pk.v;
  };
  auto issueB = [&](int kt, int buf) {
#pragma unroll
    for (int j = 0; j < 2; ++j) {
      const int c = t + j * 256;
      const int u2 = c >> 2, h = (c & 3) ^ ((u2 >> 1) & 3);
      gload16(Bpan + (size_t)kt * UDIM * 32 + u2 * 32 + h * 8,
              (char*)Bb[buf] + (c & ~63) * 16);
    }
  };

  f32x4 acc[2][4];
  const f32x4 z4 = {0.f, 0.f, 0.f, 0.f};
#pragma unroll
  for (int a = 0; a < 2; ++a)
#pragma unroll
    for (int b = 0; b < 4; ++b) acc[a][b] = z4;

  issueA(0); issueB(0, 0); writeA(0);
  __syncthreads();
  int cur = 0;
  for (int kt = 0; kt < 32; ++kt) {
    const int nb = cur ^ 1;
    if (kt < 31) { issueA(kt + 1); issueB(kt + 1, nb); }
    bf16x8 af[2], bf_[4];
#pragma unroll
    for (int mt = 0; mt < 2; ++mt) {
      const int r = wr * 32 + mt * 16 + ln15;
      af[mt] = *(const bf16x8*)((const char*)Ab[cur] + r * 64 + (g ^ ((r >> 1) & 3)) * 16);
    }
#pragma unroll
    for (int nt = 0; nt < 4; ++nt) {
      const int c2 = wc * 64 + nt * 16 + ln15;
      bf_[nt] = *(const bf16x8*)((const char*)Bb[cur] + c2 * 64 + (g ^ ((c2 >> 1) & 3)) * 16);
    }
#pragma unroll
    for (int mt = 0; mt < 2; ++mt)
#pragma unroll
      for (int nt = 0; nt < 4; ++nt)
        acc[mt][nt] = __builtin_amdgcn_mfma_f32_16x16x32_bf16(af[mt], bf_[nt], acc[mt][nt], 0, 0, 0);
    if (kt < 31) writeA(nb);
    __syncthreads();
    cur = nb;
  }

  // epilogue: +b1, swish (rcp-based), store bf16 into Hp panel-major
  float bv[4];
#pragma unroll
  for (int nt = 0; nt < 4; ++nt)
    bv[nt] = b1[e * UDIM + Nt * 128 + wc * 64 + nt * 16 + ln15];
#pragma unroll
  for (int mt = 0; mt < 2; ++mt) {
#pragma unroll
    for (int nt = 0; nt < 4; ++nt) {
      const int colg = Nt * 128 + wc * 64 + nt * 16 + ln15;
      unsigned short* hp = Hp + ((size_t)(Mt * 16 + (colg >> 5)) * 64) * 32 + (colg & 31);
#pragma unroll
      for (int r = 0; r < 4; ++r) {
        const int row = wr * 32 + mt * 16 + g * 4 + r;
        const float a = acc[mt][nt][r] + bv[nt];
        hp[(size_t)row * 32] = f2bf(a * __builtin_amdgcn_rcpf(1.f + __expf(-a)));
      }
    }
  }
}

// ---- GEMM2: Z = H @ proj[e]; fused sigmoid->RBF->ctrl->scale->scatter ------
// 64x64 tile, BK=32, 4 waves (2x2, each 32x32 out), 16KB LDS dbuf -> ~4 blk/CU.

__global__ __launch_bounds__(256) void k_gemm2(
    const unsigned short* __restrict__ Hp, const unsigned short* __restrict__ projp,
    const float* __restrict__ ctrl, const float* __restrict__ scaling,
    const int* __restrict__ perm_p, const int* __restrict__ tile_expert,
    const int* __restrict__ tile_rowlim, float* __restrict__ out) {
  __shared__ __align__(16) short Ab[2][64 * 32];
  __shared__ __align__(16) short Bb[2][64 * 32];
  __shared__ int tok_s[64];

  const int Mt = blockIdx.x;
  const int e = tile_expert[Mt];
  if (e < 0) return;
  const int Nt = blockIdx.y;  // 0..7 (64-col slices)
  const int rowlim = tile_rowlim[Mt];

  const int t = threadIdx.x;
  const int w = t >> 6, wr = w >> 1, wc = w & 1;
  const int lane = t & 63, ln15 = lane & 15, g = lane >> 4;

  if (t < 64) tok_s[t] = perm_p[Mt * 64 + (t < rowlim ? t : 0)];
  __syncthreads();

  const int srow = t >> 2;
  const int sh = (t & 3) ^ ((srow >> 1) & 3);
  const unsigned short* Apan = Hp + ((size_t)Mt * 16 * 64) * 32;
  const unsigned short* Bpan = projp + ((size_t)e * 16 * UDIM + Nt * 64) * 32;

  auto stage = [&](int kt, int buf) {
    gload16(Apan + (size_t)kt * 64 * 32 + srow * 32 + sh * 8,
            (char*)Ab[buf] + (t & ~63) * 16);
    gload16(Bpan + (size_t)kt * UDIM * 32 + srow * 32 + sh * 8,
            (char*)Bb[buf] + (t & ~63) * 16);
  };

  f32x4 acc[2][2];
  const f32x4 z4 = {0.f, 0.f, 0.f, 0.f};
  acc[0][0] = z4; acc[0][1] = z4; acc[1][0] = z4; acc[1][1] = z4;

  stage(0, 0);
  __syncthreads();
  int cur = 0;
  for (int kt = 0; kt < 16; ++kt) {
    const int nb = cur ^ 1;
    if (kt < 15) stage(kt + 1, nb);
    bf16x8 af[2], bf_[2];
#pragma unroll
    for (int mt = 0; mt < 2; ++mt) {
      const int r = wr * 32 + mt * 16 + ln15;
      af[mt] = *(const bf16x8*)((const char*)Ab[cur] + r * 64 + (g ^ ((r >> 1) & 3)) * 16);
    }
#pragma unroll
    for (int nt = 0; nt < 2; ++nt) {
      const int c2 = wc * 32 + nt * 16 + ln15;
      bf_[nt] = *(const bf16x8*)((const char*)Bb[cur] + c2 * 64 + (g ^ ((c2 >> 1) & 3)) * 16);
    }
#pragma unroll
    for (int mt = 0; mt < 2; ++mt)
#pragma unroll
      for (int nt = 0; nt < 2; ++nt)
        acc[mt][nt] = __builtin_amdgcn_mfma_f32_16x16x32_bf16(af[mt], bf_[nt], acc[mt][nt], 0, 0, 0);
    __syncthreads();
    cur = nb;
  }

  // epilogue: sigmoid -> RBF via geometric recurrence -> ctrl dot -> scale.
  // basis_b = exp(-32(xn-b/7)^2); ratio q_{b+1}/q_b = R*M^b with
  // R = exp(64xn/7 - 32/49), M = exp(-64/49). 2 exps + 2 rcp per output.
  const float M = 0.27086949f;  // exp(-64/49)
  float cv[2][8], sc[2];
#pragma unroll
  for (int nt = 0; nt < 2; ++nt) {
    const int colg = Nt * 64 + wc * 32 + nt * 16 + ln15;
    sc[nt] = scaling[e * UDIM + colg];
#pragma unroll
    for (int b = 0; b < 8; ++b) cv[nt][b] = ctrl[((size_t)e * 8 + b) * UDIM + colg];
  }
#pragma unroll
  for (int mt = 0; mt < 2; ++mt) {
#pragma unroll
    for (int r = 0; r < 4; ++r) {
      const int row = wr * 32 + mt * 16 + g * 4 + r;
      if (row < rowlim) {
        const int tok = tok_s[row];
#pragma unroll
        for (int nt = 0; nt < 2; ++nt) {
          const int colg = Nt * 64 + wc * 32 + nt * 16 + ln15;
          const float z = acc[mt][nt][r];
          const float xn = __builtin_amdgcn_rcpf(1.f + __expf(-z));
          float q = __expf(-32.f * xn * xn);                       // basis_0
          float rr = __expf(xn * (64.f / 7.f) - (32.f / 49.f));    // step ratio
          float s = 0.f, dc = 0.f;
#pragma unroll
          for (int b = 0; b < 8; ++b) {
            s += q;
            dc = fmaf(q, cv[nt][b], dc);
            q *= rr;
            rr *= M;
          }
          out[(size_t)tok * UDIM + colg] = dc * __builtin_amdgcn_rcpf(s + 1e-6f) * sc[nt];
        }
      }
    }
  }
}

// ---- host launch -----------------------------------------------------------

extern "C" void kernel_launch(void* const* d_in, const int* in_sizes, int n_in,
                              void* d_out, int out_size, void* d_ws, size_t ws_size,
                              hipStream_t stream) {
  const float* x       = (const float*)d_in[0];
  const float* W1      = (const float*)d_in[1];
  const float* b1      = (const float*)d_in[2];
  const float* proj    = (const float*)d_in[3];
  const float* ctrl    = (const float*)d_in[4];
  const float* scaling = (const float*)d_in[5];
  const float* Wg      = (const float*)d_in[6];
  const float* bg      = (const float*)d_in[7];
  float* out = (float*)d_out;
  char* ws = (char*)d_ws;

  // workspace layout (~21 MB)
  int* eidx        = (int*)(ws + 0);                 // 32KB
  int* perm_p      = (int*)(ws + 32768);             // 8704*4
  int* tile_expert = (int*)(ws + 69632 + 64);        // 544B
  int* tile_rowlim = (int*)(ws + 69632 + 640);       // 544B
  unsigned short* W1p   = (unsigned short*)(ws + 131072);                       // 8MB
  unsigned short* projp = (unsigned short*)(ws + 131072 + 8388608);             // 4MB
  unsigned short* Hp    = (unsigned short*)(ws + 131072 + 8388608 + 4194304);   // 8.9MB

  k_prep<<<NTOK / 4, 256, 0, stream>>>(x, Wg, bg, eidx);
  k_pack<<<dim3(UDIM / 64, DDIM / 64, 16), 256, 0, stream>>>(W1, proj, W1p, projp);
  k_sort<<<1, 1024, 0, stream>>>(eidx, perm_p, tile_expert, tile_rowlim);
  k_gemm1<<<dim3(MT_MAX, UDIM / 128), 256, 0, stream>>>(x, W1p, b1, perm_p,
                                                        tile_expert, tile_rowlim, Hp);
  k_gemm2<<<dim3(MT_MAX, UDIM / 64), 256, 0, stream>>>(Hp, projp, ctrl, scaling, perm_p,
                                                       tile_expert, tile_rowlim, out);
}

// Round 9
// 66.832 us; speedup vs baseline: 3.6785x; 1.1090x over previous
//
#include <hip/hip_runtime.h>
#include <hip/hip_bf16.h>
#include <stdint.h>

// Problem constants: N=8192 tokens, D=1024, U=512, E=8, B=8 bases.
#define NTOK 8192
#define DDIM 1024
#define UDIM 512
#define NEXP 8
#define MT_MAX 136   // max padded 64-row M-tiles: 8192/64 + 7 partials + slack

typedef __attribute__((ext_vector_type(8))) short bf16x8;
typedef __attribute__((ext_vector_type(4))) float f32x4;

// ---- helpers ---------------------------------------------------------------

__device__ __forceinline__ unsigned short f2bf(float f) {
  unsigned int u = __float_as_uint(f);
  u += 0x7FFFu + ((u >> 16) & 1u);
  return (unsigned short)(u >> 16);
}

__device__ __forceinline__ void gload16(const void* g, void* lds) {
  // async global->LDS, 16B/lane; LDS dest = wave-uniform base + lane*16 (HW rule);
  // global source address is per-lane (gather allowed).
  __builtin_amdgcn_global_load_lds(
      (__attribute__((address_space(1))) void*)(uintptr_t)g,
      (__attribute__((address_space(3))) void*)(uint32_t)(uintptr_t)lds,
      16, 0, 0);
}

// ---- fused prep+pack: block-range split ------------------------------------
// blocks [0,2048): gating (f32 logits, argmax, NO atomics) + x -> bf16
// blocks [2048,4096): weight packing [E][R][C] f32 -> [kt][C][32] bf16 panels

__global__ __launch_bounds__(256) void k_prep_pack(
    const float* __restrict__ x, const float* __restrict__ Wg,
    const float* __restrict__ bg, const float* __restrict__ W1,
    const float* __restrict__ proj, unsigned short* __restrict__ xbf,
    int* __restrict__ eidx, unsigned short* __restrict__ W1p,
    unsigned short* __restrict__ projp) {
  __shared__ __align__(16) char smem[8 * 1040 * 4];  // union: WgT | pack tile
  const int t = threadIdx.x;

  if (blockIdx.x < 2048) {
    // ---- gating + bf16 conversion (4 token-waves / block) ----
    float (*WgT)[1040] = (float(*)[1040])smem;
#pragma unroll
    for (int r = 0; r < 32; ++r)
      WgT[t & 7][r * 32 + (t >> 3)] = Wg[r * 256 + t];
    __syncthreads();

    const int lane = t & 63;
    const int n = (blockIdx.x << 2) + (t >> 6);
    const float* xr = x + (size_t)n * DDIM;
    unsigned short* xo = xbf + (size_t)n * DDIM;
    float acc[8] = {0.f, 0.f, 0.f, 0.f, 0.f, 0.f, 0.f, 0.f};
#pragma unroll
    for (int c = 0; c < 4; ++c) {
      const int d = c * 256 + lane * 4;
      const float4 xv = *(const float4*)(xr + d);
      ushort4 o;
      o.x = f2bf(xv.x); o.y = f2bf(xv.y); o.z = f2bf(xv.z); o.w = f2bf(xv.w);
      *(ushort4*)(xo + d) = o;
#pragma unroll
      for (int e = 0; e < 8; ++e) {
        const float4 wv = *(const float4*)(&WgT[e][d]);
        acc[e] = fmaf(xv.x, wv.x, acc[e]);
        acc[e] = fmaf(xv.y, wv.y, acc[e]);
        acc[e] = fmaf(xv.z, wv.z, acc[e]);
        acc[e] = fmaf(xv.w, wv.w, acc[e]);
      }
    }
#pragma unroll
    for (int e = 0; e < 8; ++e) {
#pragma unroll
      for (int o = 32; o > 0; o >>= 1) acc[e] += __shfl_xor(acc[e], o, 64);
    }
    if (lane == 0) {
      int best = 0;
      float bv = acc[0] + bg[0];
#pragma unroll
      for (int e2 = 1; e2 < 8; ++e2) {
        const float v = acc[e2] + bg[e2];
        if (v > bv) { bv = v; best = e2; }  // strict > = np.argmax first-index ties
      }
      eidx[n] = best;
    }
  } else {
    // ---- weight packing ----
    float (*tile)[65] = (float(*)[65])smem;
    const int id = blockIdx.x - 2048;
    const int c0 = (id & 7) << 6;
    const int r0 = ((id >> 3) & 15) << 6;
    const int z = id >> 7;  // 0..15
    const int R = (z < 8) ? DDIM : UDIM;
    if (r0 >= R) return;
    const float* src = (z < 8) ? (W1 + (size_t)z * DDIM * UDIM)
                               : (proj + (size_t)(z - 8) * UDIM * UDIM);
    unsigned short* dst = (z < 8) ? (W1p + (size_t)z * DDIM * UDIM)
                                  : (projp + (size_t)(z - 8) * UDIM * UDIM);
#pragma unroll
    for (int i = 0; i < 4; ++i) {
      const int ri = (t >> 4) + i * 16;
      const int ci = (t & 15) * 4;
      const float4 v = *(const float4*)(src + (size_t)(r0 + ri) * UDIM + c0 + ci);
      tile[ri][ci] = v.x; tile[ri][ci + 1] = v.y; tile[ri][ci + 2] = v.z; tile[ri][ci + 3] = v.w;
    }
    __syncthreads();
    const int cc = t >> 2, ch = t & 3;
#pragma unroll
    for (int j = 0; j < 2; ++j) {
      const int kt = (r0 >> 5) + j;
      union { bf16x8 v; unsigned short u[8]; } pk;
#pragma unroll
      for (int q = 0; q < 8; ++q) pk.u[q] = f2bf(tile[j * 32 + ch * 8 + q][cc]);
      *(bf16x8*)(dst + ((size_t)kt * UDIM + c0 + cc) * 32 + ch * 8) = pk.v;
    }
  }
}

// ---- sort: histogram + scan + stable scatter + tile maps, ZERO atomics -----

__global__ __launch_bounds__(1024) void k_sort(const int* __restrict__ eidx,
                                               int* __restrict__ perm_p,
                                               int* __restrict__ tile_expert,
                                               int* __restrict__ tile_rowlim) {
  __shared__ int hist[8][1024];
  __shared__ int tbase[9];
  const int t = threadIdx.x;

  int my[8], c[8] = {0, 0, 0, 0, 0, 0, 0, 0};
#pragma unroll
  for (int i = 0; i < 8; ++i) {
    my[i] = eidx[t * 8 + i];
#pragma unroll
    for (int b = 0; b < 8; ++b) c[b] += (my[i] == b);
  }
#pragma unroll
  for (int b = 0; b < 8; ++b) hist[b][t] = c[b];
  __syncthreads();

  for (int off = 1; off < 1024; off <<= 1) {
    int v[8];
#pragma unroll
    for (int b = 0; b < 8; ++b) v[b] = (t >= off) ? hist[b][t - off] : 0;
    __syncthreads();
#pragma unroll
    for (int b = 0; b < 8; ++b) hist[b][t] += v[b];
    __syncthreads();
  }

  if (t == 0) {
    int run = 0;
    for (int e = 0; e < 8; ++e) { tbase[e] = run; run += (hist[e][1023] + 63) >> 6; }
    tbase[8] = run;
  }
  __syncthreads();

  int base[8];
#pragma unroll
  for (int b = 0; b < 8; ++b) base[b] = (tbase[b] << 6) + hist[b][t] - c[b];
#pragma unroll
  for (int b = 0; b < 8; ++b) {
    int p = base[b];
#pragma unroll
    for (int i = 0; i < 8; ++i)
      if (my[i] == b) perm_p[p++] = t * 8 + i;
  }

  if (t < MT_MAX) {
    int e = -1, rl = 0;
#pragma unroll
    for (int q = 0; q < 8; ++q) {
      if (t >= tbase[q] && t < tbase[q + 1]) {
        e = q;
        const int r = hist[q][1023] - (t - tbase[q]) * 64;
        rl = r < 64 ? r : 64;
      }
    }
    tile_expert[t] = e;
    tile_rowlim[t] = rl;
  }
}

// ---- GEMM1: H = swish(xbf[tok] @ W1[e] + b1[e]) -> Hp panels bf16 ----------
// 64x64 tile, BK=32, 4 waves, 16KB LDS dbuf, all staging via global_load_lds.
// 1D grid 1088 = 8 XCD chunks x 17 Mt x 8 Nt (L2-local weight/Hp panels).

__global__ __launch_bounds__(256) void k_gemm1(
    const unsigned short* __restrict__ xbf, const unsigned short* __restrict__ W1p,
    const float* __restrict__ b1, const int* __restrict__ perm_p,
    const int* __restrict__ tile_expert, const int* __restrict__ tile_rowlim,
    unsigned short* __restrict__ Hp) {
  __shared__ __align__(16) short Ab[2][64 * 32];
  __shared__ __align__(16) short Bb[2][64 * 32];
  __shared__ int rows_s[64];

  const int orig = blockIdx.x;                      // 0..1087
  const int wg = (orig & 7) * (MT_MAX * 8 / 8) + (orig >> 3);
  const int Mt = wg >> 3, Nt = wg & 7;
  const int e = tile_expert[Mt];
  if (e < 0) return;
  const int rowlim = tile_rowlim[Mt];

  const int t = threadIdx.x;
  const int w = t >> 6, wr = w >> 1, wc = w & 1;
  const int lane = t & 63, ln15 = lane & 15, g = lane >> 4;

  if (t < 64) rows_s[t] = perm_p[Mt * 64 + (t < rowlim ? t : 0)];
  __syncthreads();

  const int srow = t >> 2;                       // staged row/col 0..63
  const int sh = (t & 3) ^ ((srow >> 1) & 3);    // pre-swizzled source chunk
  const unsigned short* arow = xbf + (size_t)rows_s[srow] * DDIM + sh * 8;
  const unsigned short* Bpan = W1p + ((size_t)e * 32 * UDIM + Nt * 64) * 32;

  auto stage = [&](int kt, int buf) {
    gload16(arow + kt * 32, (char*)Ab[buf] + (t & ~63) * 16);
    gload16(Bpan + (size_t)kt * UDIM * 32 + srow * 32 + sh * 8,
            (char*)Bb[buf] + (t & ~63) * 16);
  };

  f32x4 acc[2][2];
  const f32x4 z4 = {0.f, 0.f, 0.f, 0.f};
  acc[0][0] = z4; acc[0][1] = z4; acc[1][0] = z4; acc[1][1] = z4;

  stage(0, 0);
  __syncthreads();
  int cur = 0;
  for (int kt = 0; kt < 32; ++kt) {
    const int nb = cur ^ 1;
    if (kt < 31) stage(kt + 1, nb);
    bf16x8 af[2], bf_[2];
#pragma unroll
    for (int mt = 0; mt < 2; ++mt) {
      const int r = wr * 32 + mt * 16 + ln15;
      af[mt] = *(const bf16x8*)((const char*)Ab[cur] + r * 64 + (g ^ ((r >> 1) & 3)) * 16);
    }
#pragma unroll
    for (int nt = 0; nt < 2; ++nt) {
      const int c2 = wc * 32 + nt * 16 + ln15;
      bf_[nt] = *(const bf16x8*)((const char*)Bb[cur] + c2 * 64 + (g ^ ((c2 >> 1) & 3)) * 16);
    }
#pragma unroll
    for (int mt = 0; mt < 2; ++mt)
#pragma unroll
      for (int nt = 0; nt < 2; ++nt)
        acc[mt][nt] = __builtin_amdgcn_mfma_f32_16x16x32_bf16(af[mt], bf_[nt], acc[mt][nt], 0, 0, 0);
    __syncthreads();
    cur = nb;
  }

  // epilogue: +b1, swish (rcp-based), store bf16 into Hp panel-major
  float bv[2];
#pragma unroll
  for (int nt = 0; nt < 2; ++nt)
    bv[nt] = b1[e * UDIM + Nt * 64 + wc * 32 + nt * 16 + ln15];
#pragma unroll
  for (int mt = 0; mt < 2; ++mt) {
#pragma unroll
    for (int nt = 0; nt < 2; ++nt) {
      const int colg = Nt * 64 + wc * 32 + nt * 16 + ln15;
      unsigned short* hp = Hp + ((size_t)(Mt * 16 + (colg >> 5)) * 64) * 32 + (colg & 31);
#pragma unroll
      for (int r = 0; r < 4; ++r) {
        const int row = wr * 32 + mt * 16 + g * 4 + r;
        const float a = acc[mt][nt][r] + bv[nt];
        hp[(size_t)row * 32] = f2bf(a * __builtin_amdgcn_rcpf(1.f + __expf(-a)));
      }
    }
  }
}

// ---- GEMM2: Z = H @ proj[e]; fused sigmoid->RBF->ctrl->scale->scatter ------
// 64x64 tile, BK=32, 4 waves, 16KB LDS dbuf; same XCD-chunked 1D grid.

__global__ __launch_bounds__(256) void k_gemm2(
    const unsigned short* __restrict__ Hp, const unsigned short* __restrict__ projp,
    const float* __restrict__ ctrl, const float* __restrict__ scaling,
    const int* __restrict__ perm_p, const int* __restrict__ tile_expert,
    const int* __restrict__ tile_rowlim, float* __restrict__ out) {
  __shared__ __align__(16) short Ab[2][64 * 32];
  __shared__ __align__(16) short Bb[2][64 * 32];
  __shared__ int tok_s[64];

  const int orig = blockIdx.x;
  const int wg = (orig & 7) * (MT_MAX * 8 / 8) + (orig >> 3);
  const int Mt = wg >> 3, Nt = wg & 7;
  const int e = tile_expert[Mt];
  if (e < 0) return;
  const int rowlim = tile_rowlim[Mt];

  const int t = threadIdx.x;
  const int w = t >> 6, wr = w >> 1, wc = w & 1;
  const int lane = t & 63, ln15 = lane & 15, g = lane >> 4;

  if (t < 64) tok_s[t] = perm_p[Mt * 64 + (t < rowlim ? t : 0)];
  __syncthreads();

  const int srow = t >> 2;
  const int sh = (t & 3) ^ ((srow >> 1) & 3);
  const unsigned short* Apan = Hp + ((size_t)Mt * 16 * 64) * 32;
  const unsigned short* Bpan = projp + ((size_t)e * 16 * UDIM + Nt * 64) * 32;

  auto stage = [&](int kt, int buf) {
    gload16(Apan + (size_t)kt * 64 * 32 + srow * 32 + sh * 8,
            (char*)Ab[buf] + (t & ~63) * 16);
    gload16(Bpan + (size_t)kt * UDIM * 32 + srow * 32 + sh * 8,
            (char*)Bb[buf] + (t & ~63) * 16);
  };

  f32x4 acc[2][2];
  const f32x4 z4 = {0.f, 0.f, 0.f, 0.f};
  acc[0][0] = z4; acc[0][1] = z4; acc[1][0] = z4; acc[1][1] = z4;

  stage(0, 0);
  __syncthreads();
  int cur = 0;
  for (int kt = 0; kt < 16; ++kt) {
    const int nb = cur ^ 1;
    if (kt < 15) stage(kt + 1, nb);
    bf16x8 af[2], bf_[2];
#pragma unroll
    for (int mt = 0; mt < 2; ++mt) {
      const int r = wr * 32 + mt * 16 + ln15;
      af[mt] = *(const bf16x8*)((const char*)Ab[cur] + r * 64 + (g ^ ((r >> 1) & 3)) * 16);
    }
#pragma unroll
    for (int nt = 0; nt < 2; ++nt) {
      const int c2 = wc * 32 + nt * 16 + ln15;
      bf_[nt] = *(const bf16x8*)((const char*)Bb[cur] + c2 * 64 + (g ^ ((c2 >> 1) & 3)) * 16);
    }
#pragma unroll
    for (int mt = 0; mt < 2; ++mt)
#pragma unroll
      for (int nt = 0; nt < 2; ++nt)
        acc[mt][nt] = __builtin_amdgcn_mfma_f32_16x16x32_bf16(af[mt], bf_[nt], acc[mt][nt], 0, 0, 0);
    __syncthreads();
    cur = nb;
  }

  // epilogue: sigmoid -> RBF via geometric recurrence -> ctrl dot -> scale.
  const float M = 0.27086949f;  // exp(-64/49)
  float cv[2][8], sc[2];
#pragma unroll
  for (int nt = 0; nt < 2; ++nt) {
    const int colg = Nt * 64 + wc * 32 + nt * 16 + ln15;
    sc[nt] = scaling[e * UDIM + colg];
#pragma unroll
    for (int b = 0; b < 8; ++b) cv[nt][b] = ctrl[((size_t)e * 8 + b) * UDIM + colg];
  }
#pragma unroll
  for (int mt = 0; mt < 2; ++mt) {
#pragma unroll
    for (int r = 0; r < 4; ++r) {
      const int row = wr * 32 + mt * 16 + g * 4 + r;
      if (row < rowlim) {
        const int tok = tok_s[row];
#pragma unroll
        for (int nt = 0; nt < 2; ++nt) {
          const int colg = Nt * 64 + wc * 32 + nt * 16 + ln15;
          const float z = acc[mt][nt][r];
          const float xn = __builtin_amdgcn_rcpf(1.f + __expf(-z));
          float q = __expf(-32.f * xn * xn);                     // basis_0
          float rr = __expf(xn * (64.f / 7.f) - (32.f / 49.f));  // step ratio
          float s = 0.f, dc = 0.f;
#pragma unroll
          for (int b = 0; b < 8; ++b) {
            s += q;
            dc = fmaf(q, cv[nt][b], dc);
            q *= rr;
            rr *= M;
          }
          out[(size_t)tok * UDIM + colg] = dc * __builtin_amdgcn_rcpf(s + 1e-6f) * sc[nt];
        }
      }
    }
  }
}

// ---- host launch -----------------------------------------------------------

extern "C" void kernel_launch(void* const* d_in, const int* in_sizes, int n_in,
                              void* d_out, int out_size, void* d_ws, size_t ws_size,
                              hipStream_t stream) {
  const float* x       = (const float*)d_in[0];
  const float* W1      = (const float*)d_in[1];
  const float* b1      = (const float*)d_in[2];
  const float* proj    = (const float*)d_in[3];
  const float* ctrl    = (const float*)d_in[4];
  const float* scaling = (const float*)d_in[5];
  const float* Wg      = (const float*)d_in[6];
  const float* bg      = (const float*)d_in[7];
  float* out = (float*)d_out;
  char* ws = (char*)d_ws;

  // workspace layout (~37.1 MB)
  int* eidx        = (int*)(ws + 0);                 // 32KB
  int* perm_p      = (int*)(ws + 32768);             // 8704*4
  int* tile_expert = (int*)(ws + 69632 + 64);        // 544B
  int* tile_rowlim = (int*)(ws + 69632 + 640);       // 544B
  unsigned short* W1p   = (unsigned short*)(ws + 131072);                        // 8MB
  unsigned short* projp = (unsigned short*)(ws + 131072 + 8388608);              // 4MB
  unsigned short* Hp    = (unsigned short*)(ws + 131072 + 8388608 + 4194304);    // 8.9MB
  unsigned short* xbf   = (unsigned short*)(ws + 131072 + 8388608 + 4194304 + 9175040);  // 16MB

  k_prep_pack<<<4096, 256, 0, stream>>>(x, Wg, bg, W1, proj, xbf, eidx, W1p, projp);
  k_sort<<<1, 1024, 0, stream>>>(eidx, perm_p, tile_expert, tile_rowlim);
  k_gemm1<<<MT_MAX * 8, 256, 0, stream>>>(xbf, W1p, b1, perm_p,
                                          tile_expert, tile_rowlim, Hp);
  k_gemm2<<<MT_MAX * 8, 256, 0, stream>>>(Hp, projp, ctrl, scaling, perm_p,
                                          tile_expert, tile_rowlim, out);
}